// Round 1
// baseline (575.663 us; speedup 1.0000x reference)
//
#include <hip/hip_runtime.h>

#define N_NODES 100000
#define N_EDGES 1600000
#define IN_C 128
#define HID_C 128
#define OUT_C 64

// ---------------- CSR build helpers ----------------

__global__ void k_zero_i32(int* __restrict__ p, int n) {
  int i = blockIdx.x * blockDim.x + threadIdx.x;
  if (i < n) p[i] = 0;
}

__global__ void k_count_dst(const int* __restrict__ dst, int* __restrict__ cnt, int e) {
  int i = blockIdx.x * blockDim.x + threadIdx.x;
  if (i < e) atomicAdd(&cnt[dst[i]], 1);
}

// per-256-block exclusive scan; writes local-exclusive into rowptr, block total into bsums
__global__ void k_scan_block(const int* __restrict__ cnt, int* __restrict__ rowptr,
                             int* __restrict__ bsums, int n) {
  __shared__ int s[256];
  int t = threadIdx.x;
  int i = blockIdx.x * 256 + t;
  int v = (i < n) ? cnt[i] : 0;
  s[t] = v;
  __syncthreads();
  for (int off = 1; off < 256; off <<= 1) {
    int add = (t >= off) ? s[t - off] : 0;
    __syncthreads();
    s[t] += add;
    __syncthreads();
  }
  if (i < n) rowptr[i] = s[t] - v;  // exclusive
  if (t == 255) bsums[blockIdx.x] = s[255];
}

// single-block exclusive scan of block sums (nb <= 512)
__global__ void k_scan_sums(int* __restrict__ bsums, int nb) {
  __shared__ int s[512];
  int t = threadIdx.x;
  int v = (t < nb) ? bsums[t] : 0;
  s[t] = v;
  __syncthreads();
  for (int off = 1; off < 512; off <<= 1) {
    int add = (t >= off) ? s[t - off] : 0;
    __syncthreads();
    s[t] += add;
    __syncthreads();
  }
  if (t < nb) bsums[t] = s[t] - v;  // exclusive offsets
}

__global__ void k_add_off(int* __restrict__ rowptr, const int* __restrict__ bsums, int n, int e) {
  int i = blockIdx.x * blockDim.x + threadIdx.x;
  if (i < n) rowptr[i] += bsums[i >> 8];
  else if (i == n) rowptr[n] = e;
}

__global__ void k_dis(const int* __restrict__ rowptr, float* __restrict__ dis, int n) {
  int i = blockIdx.x * blockDim.x + threadIdx.x;
  if (i < n) {
    int d = rowptr[i + 1] - rowptr[i] + 1;  // + self-loop
    dis[i] = rsqrtf((float)d);
  }
}

__global__ void k_copy_i32(const int* __restrict__ a, int* __restrict__ b, int n) {
  int i = blockIdx.x * blockDim.x + threadIdx.x;
  if (i < n) b[i] = a[i];
}

__global__ void k_fill(const int* __restrict__ src, const int* __restrict__ dst,
                       int* __restrict__ cursor, int* __restrict__ col, int e) {
  int i = blockIdx.x * blockDim.x + threadIdx.x;
  if (i < e) {
    int p = atomicAdd(&cursor[dst[i]], 1);
    col[p] = src[i];
  }
}

// ---------------- dense GEMM: H = X @ W  (X: [n,128] f32, W: [128,NOUT]) ----------------
// block = 256 threads, tile = 64 rows x NOUT cols. x tile staged in LDS, W from L1/L2.

template <int NOUT>
__global__ __launch_bounds__(256) void k_gemm(const float* __restrict__ X,
                                              const float* __restrict__ W,
                                              float* __restrict__ H, int n) {
  __shared__ float xs[64][132];  // pad to 132 floats
  const int t = threadIdx.x;
  const int tc = t & 31;   // 0..31 -> column group
  const int tr = t >> 5;   // 0..7  -> row group (8 rows each)
  const int row0 = blockIdx.x * 64;
  constexpr int CPT = NOUT / 32;  // cols per thread: 4 (NOUT=128) or 2 (NOUT=64)

  // stage 64x128 x-tile, float4 granularity
  for (int i = t; i < 64 * 32; i += 256) {
    int r = i >> 5, q = i & 31;
    float4 v = make_float4(0.f, 0.f, 0.f, 0.f);
    if (row0 + r < n) v = ((const float4*)(X + (size_t)(row0 + r) * IN_C))[q];
    *(float4*)&xs[r][q * 4] = v;
  }
  __syncthreads();

  float acc[8][CPT];
#pragma unroll
  for (int r = 0; r < 8; ++r)
#pragma unroll
    for (int c = 0; c < CPT; ++c) acc[r][c] = 0.f;

  const int c0 = tc * CPT;
  for (int k4 = 0; k4 < IN_C / 4; ++k4) {
    float4 xv[8];
#pragma unroll
    for (int r = 0; r < 8; ++r) xv[r] = *(const float4*)&xs[tr * 8 + r][k4 * 4];
#pragma unroll
    for (int kk = 0; kk < 4; ++kk) {
      float wv[CPT];
#pragma unroll
      for (int c = 0; c < CPT; ++c) wv[c] = W[(size_t)(k4 * 4 + kk) * NOUT + c0 + c];
#pragma unroll
      for (int r = 0; r < 8; ++r) {
        float xk = ((const float*)&xv[r])[kk];
#pragma unroll
        for (int c = 0; c < CPT; ++c) acc[r][c] = fmaf(xk, wv[c], acc[r][c]);
      }
    }
  }

  for (int r = 0; r < 8; ++r) {
    int row = row0 + tr * 8 + r;
    if (row < n) {
#pragma unroll
      for (int c = 0; c < CPT; ++c) H[(size_t)row * NOUT + c0 + c] = acc[r][c];
    }
  }
}

// ---------------- sparse aggregation: out[i] = sum_{s in N(i)} h[s]*dis[s]*dis[i] + h[i]*dis[i]^2 + b
// one block per destination node, one thread per channel (coalesced row gathers, no atomics)

template <int C, bool RELU>
__global__ void k_agg(const float* __restrict__ h, const int* __restrict__ rowptr,
                      const int* __restrict__ col, const float* __restrict__ dis,
                      const float* __restrict__ bias, float* __restrict__ out) {
  const int i = blockIdx.x;
  const int c = threadIdx.x;
  const float di = dis[i];
  float acc = h[(size_t)i * C + c] * (di * di);  // self-loop term
  const int beg = rowptr[i];
  const int end = rowptr[i + 1];
  for (int j = beg; j < end; ++j) {
    int s = col[j];
    float wgt = dis[s] * di;
    acc = fmaf(h[(size_t)s * C + c], wgt, acc);
  }
  acc += bias[c];
  if (RELU) acc = fmaxf(acc, 0.f);
  out[(size_t)i * C + c] = acc;
}

// ---------------- launch ----------------

extern "C" void kernel_launch(void* const* d_in, const int* in_sizes, int n_in,
                              void* d_out, int out_size, void* d_ws, size_t ws_size,
                              hipStream_t stream) {
  const float* x  = (const float*)d_in[0];
  const int*   ei = (const int*)d_in[1];
  const float* W1 = (const float*)d_in[2];
  const float* b1 = (const float*)d_in[3];
  const float* W2 = (const float*)d_in[4];
  const float* b2 = (const float*)d_in[5];
  float* out = (float*)d_out;

  const int N = N_NODES, E = N_EDGES;
  const int* esrc = ei;       // edge_index[0]
  const int* edst = ei + E;   // edge_index[1]

  char* w = (char*)d_ws;
  auto alloc = [&](size_t bytes) -> char* {
    char* p = w;
    w += (bytes + 255) & ~(size_t)255;
    return p;
  };
  float* dis   = (float*)alloc((size_t)N * 4);
  int* rowptr  = (int*)alloc((size_t)(N + 1) * 4);
  int* cursor  = (int*)alloc((size_t)N * 4);
  int* bsums   = (int*)alloc(512 * 4);
  int* col     = (int*)alloc((size_t)E * 4);
  float* h1    = (float*)alloc((size_t)N * HID_C * 4);
  float* g1    = (float*)alloc((size_t)N * HID_C * 4);
  float* h2    = h1;  // reuse: h1 dead after first aggregation

  const int nb = (N + 255) / 256;        // 391
  const int eb = (E + 255) / 256;        // 6250

  // CSR build (shared by both layers)
  k_zero_i32<<<nb, 256, 0, stream>>>(cursor, N);
  k_count_dst<<<eb, 256, 0, stream>>>(edst, cursor, E);
  k_scan_block<<<nb, 256, 0, stream>>>(cursor, rowptr, bsums, N);
  k_scan_sums<<<1, 512, 0, stream>>>(bsums, nb);
  k_add_off<<<(N + 1 + 255) / 256, 256, 0, stream>>>(rowptr, bsums, N, E);
  k_dis<<<nb, 256, 0, stream>>>(rowptr, dis, N);
  k_copy_i32<<<nb, 256, 0, stream>>>(rowptr, cursor, N);
  k_fill<<<eb, 256, 0, stream>>>(esrc, edst, cursor, col, E);

  // layer 1
  k_gemm<HID_C><<<(N + 63) / 64, 256, 0, stream>>>(x, W1, h1, N);
  k_agg<HID_C, true><<<N, HID_C, 0, stream>>>(h1, rowptr, col, dis, b1, g1);
  // layer 2
  k_gemm<OUT_C><<<(N + 63) / 64, 256, 0, stream>>>(g1, W2, h2, N);
  k_agg<OUT_C, false><<<N, OUT_C, 0, stream>>>(h2, rowptr, col, dis, b2, out);
}

// Round 2
// 417.737 us; speedup vs baseline: 1.3781x; 1.3781x over previous
//
#include <hip/hip_runtime.h>

#define N_NODES 100000
#define N_EDGES 1600000
#define IN_C 128
#define HID_C 128
#define OUT_C 64

// ---- bf16 helpers (RTN-even pack, cheap shift decode) ----
static __device__ __forceinline__ unsigned int f2bf(float f) {
  union { float f; unsigned u; } v; v.f = f;
  unsigned r = v.u + 0x7fffu + ((v.u >> 16) & 1u);
  return r >> 16;
}
static __device__ __forceinline__ float bflo(unsigned u) {
  union { unsigned u; float f; } v; v.u = u << 16; return v.f;
}
static __device__ __forceinline__ float bfhi(unsigned u) {
  union { unsigned u; float f; } v; v.u = u & 0xffff0000u; return v.f;
}

// ---------------- CSR build ----------------

__global__ void k_count_dst(const int* __restrict__ dst, int* __restrict__ cnt, int e) {
  int i = blockIdx.x * blockDim.x + threadIdx.x;
  if (i < e) atomicAdd(&cnt[dst[i]], 1);
}

// per-256-block exclusive scan of cnt; also emits dis = rsqrt(cnt+1)
__global__ void k_scan_block(const int* __restrict__ cnt, int* __restrict__ rowptr,
                             int* __restrict__ bsums, float* __restrict__ dis, int n) {
  __shared__ int s[256];
  int t = threadIdx.x;
  int i = blockIdx.x * 256 + t;
  int v = (i < n) ? cnt[i] : 0;
  if (i < n) dis[i] = rsqrtf((float)(v + 1));  // + self-loop
  s[t] = v;
  __syncthreads();
  for (int off = 1; off < 256; off <<= 1) {
    int add = (t >= off) ? s[t - off] : 0;
    __syncthreads();
    s[t] += add;
    __syncthreads();
  }
  if (i < n) rowptr[i] = s[t] - v;  // local exclusive
  if (t == 255) bsums[blockIdx.x] = s[255];
}

__global__ void k_scan_sums(int* __restrict__ bsums, int nb) {
  __shared__ int s[512];
  int t = threadIdx.x;
  int v = (t < nb) ? bsums[t] : 0;
  s[t] = v;
  __syncthreads();
  for (int off = 1; off < 512; off <<= 1) {
    int add = (t >= off) ? s[t - off] : 0;
    __syncthreads();
    s[t] += add;
    __syncthreads();
  }
  if (t < nb) bsums[t] = s[t] - v;
}

// finalize rowptr and init fill-cursor in one pass
__global__ void k_add_off(int* __restrict__ rowptr, const int* __restrict__ bsums,
                          int* __restrict__ cursor, int n, int e) {
  int i = blockIdx.x * blockDim.x + threadIdx.x;
  if (i < n) {
    int v = rowptr[i] + bsums[i >> 8];
    rowptr[i] = v;
    cursor[i] = v;
  } else if (i == n) {
    rowptr[n] = e;
  }
}

__global__ void k_fill(const int* __restrict__ src, const int* __restrict__ dst,
                       int* __restrict__ cursor, int* __restrict__ col, int e) {
  int i = blockIdx.x * blockDim.x + threadIdx.x;
  if (i < e) {
    int p = atomicAdd(&cursor[dst[i]], 1);
    col[p] = src[i];
  }
}

// ---------------- GEMM: Hs = pack_bf16( (X @ W) * dis[row] ) ----------------
// X: [n,128] f32; W: [128,NOUT]; Hs: packed 2-ch bf16 per uint.

template <int NOUT>
__global__ __launch_bounds__(256) void k_gemm_bf(const float* __restrict__ X,
                                                 const float* __restrict__ W,
                                                 const float* __restrict__ dis,
                                                 unsigned int* __restrict__ Hs, int n) {
  __shared__ float xs[64][132];
  const int t = threadIdx.x;
  const int tc = t & 31;
  const int tr = t >> 5;
  const int row0 = blockIdx.x * 64;
  constexpr int CPT = NOUT / 32;  // 4 (NOUT=128) or 2 (NOUT=64)

  for (int i = t; i < 64 * 32; i += 256) {
    int r = i >> 5, q = i & 31;
    float4 v = make_float4(0.f, 0.f, 0.f, 0.f);
    if (row0 + r < n) v = ((const float4*)(X + (size_t)(row0 + r) * IN_C))[q];
    *(float4*)&xs[r][q * 4] = v;
  }
  __syncthreads();

  float acc[8][CPT] = {};
  const int c0 = tc * CPT;
  for (int k4 = 0; k4 < IN_C / 4; ++k4) {
    float4 xv[8];
#pragma unroll
    for (int r = 0; r < 8; ++r) xv[r] = *(const float4*)&xs[tr * 8 + r][k4 * 4];
#pragma unroll
    for (int kk = 0; kk < 4; ++kk) {
      float wv[CPT];
#pragma unroll
      for (int c = 0; c < CPT; ++c) wv[c] = W[(size_t)(k4 * 4 + kk) * NOUT + c0 + c];
#pragma unroll
      for (int r = 0; r < 8; ++r) {
        float xk = ((const float*)&xv[r])[kk];
#pragma unroll
        for (int c = 0; c < CPT; ++c) acc[r][c] = fmaf(xk, wv[c], acc[r][c]);
      }
    }
  }

  for (int r = 0; r < 8; ++r) {
    int row = row0 + tr * 8 + r;
    if (row < n) {
      float sc = dis[row];
      unsigned int pk[CPT / 2];
#pragma unroll
      for (int p = 0; p < CPT / 2; ++p) {
        unsigned lo = f2bf(acc[r][2 * p] * sc);
        unsigned hi = f2bf(acc[r][2 * p + 1] * sc);
        pk[p] = lo | (hi << 16);
      }
      unsigned int* dstp = Hs + (size_t)row * (NOUT / 2) + (c0 >> 1);
      if constexpr (CPT == 4) *(uint2*)dstp = make_uint2(pk[0], pk[1]);
      else *dstp = pk[0];
    }
  }
}

// ---------------- aggregation (bf16 pre-scaled rows, f32 accum) ----------------
// out[i] = dis[i] * (h'[i] + sum_{s in N(i)} h'[s]) + b   [, relu]

// 128 channels: one wave per node, 2 ch per lane (packed uint gather, 256 B/row)
__global__ __launch_bounds__(256) void k_agg128(const unsigned int* __restrict__ Hs,
                                                const int* __restrict__ rowptr,
                                                const int* __restrict__ col,
                                                const float* __restrict__ dis,
                                                const float* __restrict__ bias,
                                                float* __restrict__ out, int n) {
  const int node = (blockIdx.x * blockDim.x + threadIdx.x) >> 6;
  const int lane = threadIdx.x & 63;
  if (node >= n) return;
  unsigned u = Hs[(size_t)node * 64 + lane];
  float a0 = bflo(u), a1 = bfhi(u);
  int j = rowptr[node];
  const int end = rowptr[node + 1];
  for (; j + 4 <= end; j += 4) {
    int s0 = col[j], s1 = col[j + 1], s2 = col[j + 2], s3 = col[j + 3];
    unsigned u0 = Hs[(size_t)s0 * 64 + lane];
    unsigned u1 = Hs[(size_t)s1 * 64 + lane];
    unsigned u2 = Hs[(size_t)s2 * 64 + lane];
    unsigned u3 = Hs[(size_t)s3 * 64 + lane];
    a0 += (bflo(u0) + bflo(u1)) + (bflo(u2) + bflo(u3));
    a1 += (bfhi(u0) + bfhi(u1)) + (bfhi(u2) + bfhi(u3));
  }
  for (; j < end; ++j) {
    unsigned uu = Hs[(size_t)col[j] * 64 + lane];
    a0 += bflo(uu);
    a1 += bfhi(uu);
  }
  const float di = dis[node];
  const int c = lane * 2;
  float r0 = fmaf(a0, di, bias[c]);
  float r1 = fmaf(a1, di, bias[c + 1]);
  r0 = fmaxf(r0, 0.f);
  r1 = fmaxf(r1, 0.f);
  *(float2*)&out[(size_t)node * 128 + c] = make_float2(r0, r1);
}

// 64 channels: half-wave per node, 2 ch per lane (128 B/row), no relu
__global__ __launch_bounds__(256) void k_agg64(const unsigned int* __restrict__ Hs,
                                               const int* __restrict__ rowptr,
                                               const int* __restrict__ col,
                                               const float* __restrict__ dis,
                                               const float* __restrict__ bias,
                                               float* __restrict__ out, int n) {
  const int node = (blockIdx.x * blockDim.x + threadIdx.x) >> 5;
  const int l = threadIdx.x & 31;
  if (node >= n) return;
  unsigned u = Hs[(size_t)node * 32 + l];
  float a0 = bflo(u), a1 = bfhi(u);
  int j = rowptr[node];
  const int end = rowptr[node + 1];
  for (; j + 4 <= end; j += 4) {
    int s0 = col[j], s1 = col[j + 1], s2 = col[j + 2], s3 = col[j + 3];
    unsigned u0 = Hs[(size_t)s0 * 32 + l];
    unsigned u1 = Hs[(size_t)s1 * 32 + l];
    unsigned u2 = Hs[(size_t)s2 * 32 + l];
    unsigned u3 = Hs[(size_t)s3 * 32 + l];
    a0 += (bflo(u0) + bflo(u1)) + (bflo(u2) + bflo(u3));
    a1 += (bfhi(u0) + bfhi(u1)) + (bfhi(u2) + bfhi(u3));
  }
  for (; j < end; ++j) {
    unsigned uu = Hs[(size_t)col[j] * 32 + l];
    a0 += bflo(uu);
    a1 += bfhi(uu);
  }
  const float di = dis[node];
  const int c = l * 2;
  float r0 = fmaf(a0, di, bias[c]);
  float r1 = fmaf(a1, di, bias[c + 1]);
  *(float2*)&out[(size_t)node * 64 + c] = make_float2(r0, r1);
}

// ---------------- launch ----------------

extern "C" void kernel_launch(void* const* d_in, const int* in_sizes, int n_in,
                              void* d_out, int out_size, void* d_ws, size_t ws_size,
                              hipStream_t stream) {
  const float* x  = (const float*)d_in[0];
  const int*   ei = (const int*)d_in[1];
  const float* W1 = (const float*)d_in[2];
  const float* b1 = (const float*)d_in[3];
  const float* W2 = (const float*)d_in[4];
  const float* b2 = (const float*)d_in[5];
  float* out = (float*)d_out;

  const int N = N_NODES, E = N_EDGES;
  const int* esrc = ei;
  const int* edst = ei + E;

  char* w = (char*)d_ws;
  auto alloc = [&](size_t bytes) -> char* {
    char* p = w;
    w += (bytes + 255) & ~(size_t)255;
    return p;
  };
  float* dis         = (float*)alloc((size_t)N * 4);
  int* rowptr        = (int*)alloc((size_t)(N + 1) * 4);
  int* cursor        = (int*)alloc((size_t)N * 4);
  int* bsums         = (int*)alloc(512 * 4);
  int* col           = (int*)alloc((size_t)E * 4);
  unsigned int* h1s  = (unsigned int*)alloc((size_t)N * (HID_C / 2) * 4);  // 25.6 MB
  float* g1          = (float*)alloc((size_t)N * HID_C * 4);               // 51.2 MB
  unsigned int* h2s  = (unsigned int*)alloc((size_t)N * (OUT_C / 2) * 4);  // 12.8 MB

  const int nb = (N + 255) / 256;
  const int eb = (E + 255) / 256;

  // CSR build (shared by both layers)
  hipMemsetAsync(cursor, 0, (size_t)N * 4, stream);
  k_count_dst<<<eb, 256, 0, stream>>>(edst, cursor, E);
  k_scan_block<<<nb, 256, 0, stream>>>(cursor, rowptr, bsums, dis, N);
  k_scan_sums<<<1, 512, 0, stream>>>(bsums, nb);
  k_add_off<<<(N + 1 + 255) / 256, 256, 0, stream>>>(rowptr, bsums, cursor, N, E);
  k_fill<<<eb, 256, 0, stream>>>(esrc, edst, cursor, col, E);

  // layer 1: h1s = bf16((x@W1)*dis) ; g1 = relu(di*(sum h1s) + b1)
  k_gemm_bf<HID_C><<<(N + 63) / 64, 256, 0, stream>>>(x, W1, dis, h1s, N);
  k_agg128<<<(N * 64 + 255) / 256, 256, 0, stream>>>(h1s, rowptr, col, dis, b1, g1, N);
  // layer 2: h2s = bf16((g1@W2)*dis) ; out = di*(sum h2s) + b2
  k_gemm_bf<OUT_C><<<(N + 63) / 64, 256, 0, stream>>>(g1, W2, dis, h2s, N);
  k_agg64<<<(N * 32 + 255) / 256, 256, 0, stream>>>(h2s, rowptr, col, dis, b2, out, N);
}

// Round 3
// 337.651 us; speedup vs baseline: 1.7049x; 1.2372x over previous
//
#include <hip/hip_runtime.h>

#define N_NODES 100000
#define N_EDGES 1600000
#define IN_C 128
#define HID_C 128
#define OUT_C 64

#define SH 8                 // bucket = dst >> 8 (256 nodes per bucket)
#define NBKT 391             // ceil(100000 / 256)
#define EPB 8192             // edges per block in phase A

// ---- bf16 helpers (RTN-even pack, cheap shift decode) ----
static __device__ __forceinline__ unsigned int f2bf(float f) {
  union { float f; unsigned u; } v; v.f = f;
  unsigned r = v.u + 0x7fffu + ((v.u >> 16) & 1u);
  return r >> 16;
}
static __device__ __forceinline__ float bflo(unsigned u) {
  union { unsigned u; float f; } v; v.u = u << 16; return v.f;
}
static __device__ __forceinline__ float bfhi(unsigned u) {
  union { unsigned u; float f; } v; v.u = u & 0xffff0000u; return v.f;
}

// ---------------- CSR build ----------------

__global__ void k_count_dst(const int* __restrict__ dst, int* __restrict__ cnt, int e) {
  int i = blockIdx.x * blockDim.x + threadIdx.x;
  if (i < e) atomicAdd(&cnt[dst[i]], 1);
}

// per-256-block exclusive scan of cnt; also emits dis = rsqrt(cnt+1)
__global__ void k_scan_block(const int* __restrict__ cnt, int* __restrict__ rowptr,
                             int* __restrict__ bsums, float* __restrict__ dis, int n) {
  __shared__ int s[256];
  int t = threadIdx.x;
  int i = blockIdx.x * 256 + t;
  int v = (i < n) ? cnt[i] : 0;
  if (i < n) dis[i] = rsqrtf((float)(v + 1));  // + self-loop
  s[t] = v;
  __syncthreads();
  for (int off = 1; off < 256; off <<= 1) {
    int add = (t >= off) ? s[t - off] : 0;
    __syncthreads();
    s[t] += add;
    __syncthreads();
  }
  if (i < n) rowptr[i] = s[t] - v;  // local exclusive
  if (t == 255) bsums[blockIdx.x] = s[255];
}

__global__ void k_scan_sums(int* __restrict__ bsums, int nb) {
  __shared__ int s[512];
  int t = threadIdx.x;
  int v = (t < nb) ? bsums[t] : 0;
  s[t] = v;
  __syncthreads();
  for (int off = 1; off < 512; off <<= 1) {
    int add = (t >= off) ? s[t - off] : 0;
    __syncthreads();
    s[t] += add;
    __syncthreads();
  }
  if (t < nb) bsums[t] = s[t] - v;
}

__global__ void k_add_off(int* __restrict__ rowptr, const int* __restrict__ bsums,
                          int n, int e) {
  int i = blockIdx.x * blockDim.x + threadIdx.x;
  if (i < n) rowptr[i] += bsums[i >> 8];
  else if (i == n) rowptr[n] = e;
}

// bucket segment starts (= rowptr at bucket boundaries) + phase-A cursors
__global__ void k_bstart(const int* __restrict__ rowptr, int* __restrict__ bstart,
                         int* __restrict__ bcur, int n) {
  int b = blockIdx.x * blockDim.x + threadIdx.x;
  if (b <= NBKT) {
    int node = b << SH;
    int v = rowptr[node > n ? n : node];
    bstart[b] = v;
    if (b < NBKT) bcur[b] = v;
  }
}

// phase A: partition edges into dst-buckets; tmp entry = src | (dst&255)<<17
__global__ __launch_bounds__(256) void k_partA(const int* __restrict__ src,
                                               const int* __restrict__ dst,
                                               int* __restrict__ bcur,
                                               unsigned* __restrict__ tmp, int e) {
  __shared__ int hist[NBKT];
  __shared__ int base[NBKT];
  const int t = threadIdx.x;
  const int e0 = blockIdx.x * EPB;
  const int e1 = (e0 + EPB < e) ? e0 + EPB : e;
  for (int i = t; i < NBKT; i += 256) hist[i] = 0;
  __syncthreads();
  for (int i = e0 + t; i < e1; i += 256)
    atomicAdd(&hist[dst[i] >> SH], 1);
  __syncthreads();
  for (int i = t; i < NBKT; i += 256) {
    int h = hist[i];
    base[i] = h ? atomicAdd(&bcur[i], h) : 0;
    hist[i] = 0;
  }
  __syncthreads();
  for (int i = e0 + t; i < e1; i += 256) {
    int d = dst[i];
    int b = d >> SH;
    int r = atomicAdd(&hist[b], 1);
    tmp[base[b] + r] = (unsigned)src[i] | ((unsigned)(d & 255) << 17);
  }
}

// phase B: within each bucket, scatter src to exact CSR slots (LDS cursors)
__global__ __launch_bounds__(256) void k_partB(const unsigned* __restrict__ tmp,
                                               const int* __restrict__ bstart,
                                               const int* __restrict__ rowptr,
                                               int* __restrict__ col, int n) {
  __shared__ int cur[256];
  const int b = blockIdx.x;
  const int t = threadIdx.x;
  const int node = (b << SH) + t;
  if (node < n) cur[t] = rowptr[node];
  __syncthreads();
  const int s0 = bstart[b], s1 = bstart[b + 1];
  for (int j = s0 + t; j < s1; j += 256) {
    unsigned v = tmp[j];
    int pos = atomicAdd(&cur[v >> 17], 1);
    col[pos] = (int)(v & 0x1FFFFu);
  }
}

// ---------------- GEMM: Hs = pack_bf16( (X @ W) * dis[row] ) ----------------

template <int NOUT>
__global__ __launch_bounds__(256) void k_gemm_bf(const float* __restrict__ X,
                                                 const float* __restrict__ W,
                                                 const float* __restrict__ dis,
                                                 unsigned int* __restrict__ Hs, int n) {
  __shared__ float xs[64][132];
  const int t = threadIdx.x;
  const int tc = t & 31;
  const int tr = t >> 5;
  const int row0 = blockIdx.x * 64;
  constexpr int CPT = NOUT / 32;  // 4 (NOUT=128) or 2 (NOUT=64)

  for (int i = t; i < 64 * 32; i += 256) {
    int r = i >> 5, q = i & 31;
    float4 v = make_float4(0.f, 0.f, 0.f, 0.f);
    if (row0 + r < n) v = ((const float4*)(X + (size_t)(row0 + r) * IN_C))[q];
    *(float4*)&xs[r][q * 4] = v;
  }
  __syncthreads();

  float acc[8][CPT] = {};
  const int c0 = tc * CPT;
  for (int k4 = 0; k4 < IN_C / 4; ++k4) {
    float4 xv[8];
#pragma unroll
    for (int r = 0; r < 8; ++r) xv[r] = *(const float4*)&xs[tr * 8 + r][k4 * 4];
#pragma unroll
    for (int kk = 0; kk < 4; ++kk) {
      float wv[CPT];
#pragma unroll
      for (int c = 0; c < CPT; ++c) wv[c] = W[(size_t)(k4 * 4 + kk) * NOUT + c0 + c];
#pragma unroll
      for (int r = 0; r < 8; ++r) {
        float xk = ((const float*)&xv[r])[kk];
#pragma unroll
        for (int c = 0; c < CPT; ++c) acc[r][c] = fmaf(xk, wv[c], acc[r][c]);
      }
    }
  }

  for (int r = 0; r < 8; ++r) {
    int row = row0 + tr * 8 + r;
    if (row < n) {
      float sc = dis[row];
      unsigned int pk[CPT / 2];
#pragma unroll
      for (int p = 0; p < CPT / 2; ++p) {
        unsigned lo = f2bf(acc[r][2 * p] * sc);
        unsigned hi = f2bf(acc[r][2 * p + 1] * sc);
        pk[p] = lo | (hi << 16);
      }
      unsigned int* dstp = Hs + (size_t)row * (NOUT / 2) + (c0 >> 1);
      if constexpr (CPT == 4) *(uint2*)dstp = make_uint2(pk[0], pk[1]);
      else *dstp = pk[0];
    }
  }
}

// ---------------- aggregation (bf16 pre-scaled rows, f32 accum) ----------------
// out[i] = dis[i] * (h'[i] + sum_{s in N(i)} h'[s]) + b   [, relu]

__global__ __launch_bounds__(256) void k_agg128(const unsigned int* __restrict__ Hs,
                                                const int* __restrict__ rowptr,
                                                const int* __restrict__ col,
                                                const float* __restrict__ dis,
                                                const float* __restrict__ bias,
                                                float* __restrict__ out, int n) {
  const int node = (blockIdx.x * blockDim.x + threadIdx.x) >> 6;
  const int lane = threadIdx.x & 63;
  if (node >= n) return;
  unsigned u = Hs[(size_t)node * 64 + lane];
  float a0 = bflo(u), a1 = bfhi(u);
  int j = rowptr[node];
  const int end = rowptr[node + 1];
  for (; j + 4 <= end; j += 4) {
    int s0 = col[j], s1 = col[j + 1], s2 = col[j + 2], s3 = col[j + 3];
    unsigned u0 = Hs[(size_t)s0 * 64 + lane];
    unsigned u1 = Hs[(size_t)s1 * 64 + lane];
    unsigned u2 = Hs[(size_t)s2 * 64 + lane];
    unsigned u3 = Hs[(size_t)s3 * 64 + lane];
    a0 += (bflo(u0) + bflo(u1)) + (bflo(u2) + bflo(u3));
    a1 += (bfhi(u0) + bfhi(u1)) + (bfhi(u2) + bfhi(u3));
  }
  for (; j < end; ++j) {
    unsigned uu = Hs[(size_t)col[j] * 64 + lane];
    a0 += bflo(uu);
    a1 += bfhi(uu);
  }
  const float di = dis[node];
  const int c = lane * 2;
  float r0 = fmaf(a0, di, bias[c]);
  float r1 = fmaf(a1, di, bias[c + 1]);
  r0 = fmaxf(r0, 0.f);
  r1 = fmaxf(r1, 0.f);
  *(float2*)&out[(size_t)node * 128 + c] = make_float2(r0, r1);
}

__global__ __launch_bounds__(256) void k_agg64(const unsigned int* __restrict__ Hs,
                                               const int* __restrict__ rowptr,
                                               const int* __restrict__ col,
                                               const float* __restrict__ dis,
                                               const float* __restrict__ bias,
                                               float* __restrict__ out, int n) {
  const int node = (blockIdx.x * blockDim.x + threadIdx.x) >> 5;
  const int l = threadIdx.x & 31;
  if (node >= n) return;
  unsigned u = Hs[(size_t)node * 32 + l];
  float a0 = bflo(u), a1 = bfhi(u);
  int j = rowptr[node];
  const int end = rowptr[node + 1];
  for (; j + 4 <= end; j += 4) {
    int s0 = col[j], s1 = col[j + 1], s2 = col[j + 2], s3 = col[j + 3];
    unsigned u0 = Hs[(size_t)s0 * 32 + l];
    unsigned u1 = Hs[(size_t)s1 * 32 + l];
    unsigned u2 = Hs[(size_t)s2 * 32 + l];
    unsigned u3 = Hs[(size_t)s3 * 32 + l];
    a0 += (bflo(u0) + bflo(u1)) + (bflo(u2) + bflo(u3));
    a1 += (bfhi(u0) + bfhi(u1)) + (bfhi(u2) + bfhi(u3));
  }
  for (; j < end; ++j) {
    unsigned uu = Hs[(size_t)col[j] * 32 + l];
    a0 += bflo(uu);
    a1 += bfhi(uu);
  }
  const float di = dis[node];
  const int c = l * 2;
  float r0 = fmaf(a0, di, bias[c]);
  float r1 = fmaf(a1, di, bias[c + 1]);
  *(float2*)&out[(size_t)node * 64 + c] = make_float2(r0, r1);
}

// ---------------- launch ----------------

extern "C" void kernel_launch(void* const* d_in, const int* in_sizes, int n_in,
                              void* d_out, int out_size, void* d_ws, size_t ws_size,
                              hipStream_t stream) {
  const float* x  = (const float*)d_in[0];
  const int*   ei = (const int*)d_in[1];
  const float* W1 = (const float*)d_in[2];
  const float* b1 = (const float*)d_in[3];
  const float* W2 = (const float*)d_in[4];
  const float* b2 = (const float*)d_in[5];
  float* out = (float*)d_out;

  const int N = N_NODES, E = N_EDGES;
  const int* esrc = ei;
  const int* edst = ei + E;

  char* w = (char*)d_ws;
  auto alloc = [&](size_t bytes) -> char* {
    char* p = w;
    w += (bytes + 255) & ~(size_t)255;
    return p;
  };
  float* dis         = (float*)alloc((size_t)N * 4);
  int* rowptr        = (int*)alloc((size_t)(N + 1) * 4);
  int* cnt           = (int*)alloc((size_t)N * 4);
  int* bsums         = (int*)alloc(512 * 4);
  int* bstart        = (int*)alloc((size_t)(NBKT + 1) * 4);
  int* bcur          = (int*)alloc((size_t)NBKT * 4);
  int* col           = (int*)alloc((size_t)E * 4);
  unsigned int* h1s  = (unsigned int*)alloc((size_t)N * (HID_C / 2) * 4);  // 25.6 MB
  float* g1          = (float*)alloc((size_t)N * HID_C * 4);               // 51.2 MB
  unsigned int* h2s  = (unsigned int*)alloc((size_t)N * (OUT_C / 2) * 4);  // 12.8 MB
  unsigned* tmp      = (unsigned*)g1;  // alias: tmp dead before agg128 writes g1

  const int nb = (N + 255) / 256;
  const int eb = (E + 255) / 256;

  // CSR build (shared by both layers)
  hipMemsetAsync(cnt, 0, (size_t)N * 4, stream);
  k_count_dst<<<eb, 256, 0, stream>>>(edst, cnt, E);
  k_scan_block<<<nb, 256, 0, stream>>>(cnt, rowptr, bsums, dis, N);
  k_scan_sums<<<1, 512, 0, stream>>>(bsums, nb);
  k_add_off<<<(N + 1 + 255) / 256, 256, 0, stream>>>(rowptr, bsums, N, E);
  k_bstart<<<(NBKT + 1 + 255) / 256, 256, 0, stream>>>(rowptr, bstart, bcur, N);
  k_partA<<<(E + EPB - 1) / EPB, 256, 0, stream>>>(esrc, edst, bcur, tmp, E);
  k_partB<<<NBKT, 256, 0, stream>>>(tmp, bstart, rowptr, col, N);

  // layer 1: h1s = bf16((x@W1)*dis) ; g1 = relu(di*(sum h1s) + b1)
  k_gemm_bf<HID_C><<<(N + 63) / 64, 256, 0, stream>>>(x, W1, dis, h1s, N);
  k_agg128<<<(N * 64 + 255) / 256, 256, 0, stream>>>(h1s, rowptr, col, dis, b1, g1, N);
  // layer 2: h2s = bf16((g1@W2)*dis) ; out = di*(sum h2s) + b2
  k_gemm_bf<OUT_C><<<(N + 63) / 64, 256, 0, stream>>>(g1, W2, dis, h2s, N);
  k_agg64<<<(N * 32 + 255) / 256, 256, 0, stream>>>(h2s, rowptr, col, dis, b2, out, N);
}

// Round 4
// 323.314 us; speedup vs baseline: 1.7805x; 1.0443x over previous
//
#include <hip/hip_runtime.h>

#define N_NODES 100000
#define N_EDGES 1600000
#define IN_C 128
#define HID_C 128
#define OUT_C 64

#define SH 8                 // bucket = dst >> 8 (256 nodes/bucket)
#define NBKT 391             // ceil(100000/256)
#define CAP 4608             // bucket capacity: mean 4096 + 8 sigma
#define EPB 8192             // edges per block in phase A

typedef __attribute__((ext_vector_type(8))) short bf16x8;
typedef __attribute__((ext_vector_type(4))) float f32x4;

// ---- bf16 helpers ----
static __device__ __forceinline__ unsigned f2bf(float f) {
  union { float f; unsigned u; } v; v.f = f;
  unsigned r = v.u + 0x7fffu + ((v.u >> 16) & 1u);
  return r >> 16;
}
static __device__ __forceinline__ float bf2f(unsigned hu) {
  union { unsigned u; float f; } v; v.u = hu << 16; return v.f;
}
static __device__ __forceinline__ float bflo(unsigned u) {
  union { unsigned u; float f; } v; v.u = u << 16; return v.f;
}
static __device__ __forceinline__ float bfhi(unsigned u) {
  union { unsigned u; float f; } v; v.u = u & 0xffff0000u; return v.f;
}

// ---------------- CSR build ----------------

// phase A fused with degree count: per-edge cnt atomics (L2-resident 400KB),
// LDS bucket histogram, bucket-major tmp at fixed capacity CAP.
__global__ __launch_bounds__(256) void k_partA(const int* __restrict__ src,
                                               const int* __restrict__ dst,
                                               int* __restrict__ cnt,
                                               int* __restrict__ bcnt,
                                               unsigned* __restrict__ tmp, int e) {
  __shared__ int hist[NBKT];
  __shared__ int base[NBKT];
  const int t = threadIdx.x;
  const int e0 = blockIdx.x * EPB;
  const int e1 = (e0 + EPB < e) ? e0 + EPB : e;
  for (int i = t; i < NBKT; i += 256) hist[i] = 0;
  __syncthreads();
  for (int i = e0 + t; i < e1; i += 256) {
    int d = dst[i];
    atomicAdd(&cnt[d], 1);
    atomicAdd(&hist[d >> SH], 1);
  }
  __syncthreads();
  for (int i = t; i < NBKT; i += 256) {
    int h = hist[i];
    base[i] = h ? atomicAdd(&bcnt[i], h) : 0;
    hist[i] = 0;
  }
  __syncthreads();
  for (int i = e0 + t; i < e1; i += 256) {
    int d = dst[i];
    int b = d >> SH;
    int r = atomicAdd(&hist[b], 1);
    int s = base[b] + r;
    if (s < CAP)  // 8-sigma safety clamp
      tmp[(size_t)b * CAP + s] = (unsigned)src[i] | ((unsigned)(d & 255) << 17);
  }
}

// per-256-block exclusive scan of cnt; also emits dis = rsqrt(cnt+1)
__global__ void k_scan_block(const int* __restrict__ cnt, int* __restrict__ rowptr,
                             int* __restrict__ bsums, float* __restrict__ dis, int n) {
  __shared__ int s[256];
  int t = threadIdx.x;
  int i = blockIdx.x * 256 + t;
  int v = (i < n) ? cnt[i] : 0;
  if (i < n) dis[i] = rsqrtf((float)(v + 1));
  s[t] = v;
  __syncthreads();
  for (int off = 1; off < 256; off <<= 1) {
    int add = (t >= off) ? s[t - off] : 0;
    __syncthreads();
    s[t] += add;
    __syncthreads();
  }
  if (i < n) rowptr[i] = s[t] - v;
  if (t == 255) bsums[blockIdx.x] = s[255];
}

__global__ void k_scan_sums(int* __restrict__ bsums, int nb) {
  __shared__ int s[512];
  int t = threadIdx.x;
  int v = (t < nb) ? bsums[t] : 0;
  s[t] = v;
  __syncthreads();
  for (int off = 1; off < 512; off <<= 1) {
    int add = (t >= off) ? s[t - off] : 0;
    __syncthreads();
    s[t] += add;
    __syncthreads();
  }
  if (t < nb) bsums[t] = s[t] - v;
}

__global__ void k_add_off(int* __restrict__ rowptr, const int* __restrict__ bsums,
                          int n, int e) {
  int i = blockIdx.x * blockDim.x + threadIdx.x;
  if (i < n) rowptr[i] += bsums[i >> 8];
  else if (i == n) rowptr[n] = e;
}

// phase B: bucket-local scatter to exact CSR slots (LDS cursors)
__global__ __launch_bounds__(256) void k_partB(const unsigned* __restrict__ tmp,
                                               const int* __restrict__ bcnt,
                                               const int* __restrict__ rowptr,
                                               int* __restrict__ col, int n) {
  __shared__ int cur[256];
  const int b = blockIdx.x;
  const int t = threadIdx.x;
  const int node = (b << SH) + t;
  cur[t] = (node < n) ? rowptr[node] : 0;
  __syncthreads();
  int m = bcnt[b];
  if (m > CAP) m = CAP;
  for (int j = t; j < m; j += 256) {
    unsigned v = tmp[(size_t)b * CAP + j];
    int pos = atomicAdd(&cur[v >> 17], 1);
    col[pos] = (int)(v & 0x1FFFFu);
  }
}

// ---------------- weight prep: transpose + split-bf16 (W = hi + lo) ----------------

__global__ void k_prepW(const float* __restrict__ W1, const float* __restrict__ W2,
                        unsigned short* __restrict__ W1h, unsigned short* __restrict__ W1l,
                        unsigned short* __restrict__ W2h, unsigned short* __restrict__ W2l) {
  int i = blockIdx.x * blockDim.x + threadIdx.x;
  if (i < IN_C * HID_C) {
    int k = i >> 7, c = i & 127;
    float w = W1[i];
    unsigned hi = f2bf(w);
    W1h[c * 128 + k] = (unsigned short)hi;
    W1l[c * 128 + k] = (unsigned short)f2bf(w - bf2f(hi));
  }
  int j = i - IN_C * HID_C;
  if (j >= 0 && j < HID_C * OUT_C) {
    int k = j >> 6, c = j & 63;
    float w = W2[j];
    unsigned hi = f2bf(w);
    W2h[c * 128 + k] = (unsigned short)hi;
    W2l[c * 128 + k] = (unsigned short)f2bf(w - bf2f(hi));
  }
}

// ---------------- MFMA GEMM layer 1: Hs = bf16( (f32 X @ W1) * dis[row] ) ----------------
// tile 64 rows x 128 cols, 4 waves (16 rows each), K=128 staged whole in LDS.

__global__ __launch_bounds__(256) void k_mfma1(const float* __restrict__ X,
                                               const unsigned short* __restrict__ Wh,
                                               const unsigned short* __restrict__ Wl,
                                               const float* __restrict__ dis,
                                               unsigned short* __restrict__ Hs, int n) {
  __shared__ unsigned short xs[64 * 136];  // bf16, row stride 136 (16B pad: bank-friendly)
  const int t = threadIdx.x;
  const int row0 = blockIdx.x * 64;
  for (int i = t; i < 64 * 32; i += 256) {
    int r = i >> 5, q = i & 31;
    float4 v = make_float4(0.f, 0.f, 0.f, 0.f);
    if (row0 + r < n) v = ((const float4*)(X + (size_t)(row0 + r) * IN_C))[q];
    unsigned p0 = f2bf(v.x) | (f2bf(v.y) << 16);
    unsigned p1 = f2bf(v.z) | (f2bf(v.w) << 16);
    *(uint2*)&xs[r * 136 + q * 4] = make_uint2(p0, p1);
  }
  __syncthreads();

  const int w = t >> 6, l = t & 63;
  const int wr = w * 16;
  const int lr = l & 15, lk = (l >> 4) * 8;
  f32x4 acc[8];
#pragma unroll
  for (int c = 0; c < 8; ++c) acc[c] = (f32x4){0.f, 0.f, 0.f, 0.f};

#pragma unroll
  for (int kb = 0; kb < 4; ++kb) {
    bf16x8 a = *(const bf16x8*)&xs[(wr + lr) * 136 + kb * 32 + lk];
#pragma unroll
    for (int c = 0; c < 8; ++c) {
      int col = c * 16 + lr;
      bf16x8 bh = *(const bf16x8*)&Wh[(size_t)col * 128 + kb * 32 + lk];
      bf16x8 bl = *(const bf16x8*)&Wl[(size_t)col * 128 + kb * 32 + lk];
      acc[c] = __builtin_amdgcn_mfma_f32_16x16x32_bf16(a, bh, acc[c], 0, 0, 0);
      acc[c] = __builtin_amdgcn_mfma_f32_16x16x32_bf16(a, bl, acc[c], 0, 0, 0);
    }
  }

  const int rbase = row0 + wr + (l >> 4) * 4;  // C/D: col=lane&15, row=(lane>>4)*4+reg
  float dv[4];
#pragma unroll
  for (int j = 0; j < 4; ++j) dv[j] = (rbase + j < n) ? dis[rbase + j] : 0.f;
#pragma unroll
  for (int c = 0; c < 8; ++c) {
    int col = c * 16 + lr;
#pragma unroll
    for (int j = 0; j < 4; ++j) {
      int row = rbase + j;
      if (row < n) Hs[(size_t)row * HID_C + col] = (unsigned short)f2bf(acc[c][j] * dv[j]);
    }
  }
}

// ---------------- MFMA GEMM layer 2: Hs = bf16( (bf16 G @ W2) * dis[row] ) ----------------

__global__ __launch_bounds__(256) void k_mfma2(const unsigned* __restrict__ G,
                                               const unsigned short* __restrict__ Wh,
                                               const unsigned short* __restrict__ Wl,
                                               const float* __restrict__ dis,
                                               unsigned short* __restrict__ Hs, int n) {
  __shared__ unsigned short xs[64 * 136];
  const int t = threadIdx.x;
  const int row0 = blockIdx.x * 64;
  for (int i = t; i < 64 * 32; i += 256) {
    int r = i >> 5, q = i & 31;
    uint2 v = make_uint2(0u, 0u);
    if (row0 + r < n) v = *(const uint2*)&G[(size_t)(row0 + r) * 64 + q * 2];
    *(uint2*)&xs[r * 136 + q * 4] = v;
  }
  __syncthreads();

  const int w = t >> 6, l = t & 63;
  const int wr = w * 16;
  const int lr = l & 15, lk = (l >> 4) * 8;
  f32x4 acc[4];
#pragma unroll
  for (int c = 0; c < 4; ++c) acc[c] = (f32x4){0.f, 0.f, 0.f, 0.f};

#pragma unroll
  for (int kb = 0; kb < 4; ++kb) {
    bf16x8 a = *(const bf16x8*)&xs[(wr + lr) * 136 + kb * 32 + lk];
#pragma unroll
    for (int c = 0; c < 4; ++c) {
      int col = c * 16 + lr;
      bf16x8 bh = *(const bf16x8*)&Wh[(size_t)col * 128 + kb * 32 + lk];
      bf16x8 bl = *(const bf16x8*)&Wl[(size_t)col * 128 + kb * 32 + lk];
      acc[c] = __builtin_amdgcn_mfma_f32_16x16x32_bf16(a, bh, acc[c], 0, 0, 0);
      acc[c] = __builtin_amdgcn_mfma_f32_16x16x32_bf16(a, bl, acc[c], 0, 0, 0);
    }
  }

  const int rbase = row0 + wr + (l >> 4) * 4;
  float dv[4];
#pragma unroll
  for (int j = 0; j < 4; ++j) dv[j] = (rbase + j < n) ? dis[rbase + j] : 0.f;
#pragma unroll
  for (int c = 0; c < 4; ++c) {
    int col = c * 16 + lr;
#pragma unroll
    for (int j = 0; j < 4; ++j) {
      int row = rbase + j;
      if (row < n) Hs[(size_t)row * OUT_C + col] = (unsigned short)f2bf(acc[c][j] * dv[j]);
    }
  }
}

// ---------------- aggregation (bf16 pre-scaled rows, f32 accum) ----------------
// layer1: G[i] = bf16x2( relu(dis[i]*(h'[i] + sum h'[s]) + b) )   (packed uint out)

__global__ __launch_bounds__(256) void k_agg128(const unsigned* __restrict__ Hs,
                                                const int* __restrict__ rowptr,
                                                const int* __restrict__ col,
                                                const float* __restrict__ dis,
                                                const float* __restrict__ bias,
                                                unsigned* __restrict__ G, int n) {
  const int node = (blockIdx.x * blockDim.x + threadIdx.x) >> 6;
  const int lane = threadIdx.x & 63;
  if (node >= n) return;
  unsigned u = Hs[(size_t)node * 64 + lane];
  float a0 = bflo(u), a1 = bfhi(u);
  int j = rowptr[node];
  const int end = rowptr[node + 1];
  for (; j + 8 <= end; j += 8) {
    int s0 = col[j], s1 = col[j + 1], s2 = col[j + 2], s3 = col[j + 3];
    int s4 = col[j + 4], s5 = col[j + 5], s6 = col[j + 6], s7 = col[j + 7];
    unsigned u0 = Hs[(size_t)s0 * 64 + lane];
    unsigned u1 = Hs[(size_t)s1 * 64 + lane];
    unsigned u2 = Hs[(size_t)s2 * 64 + lane];
    unsigned u3 = Hs[(size_t)s3 * 64 + lane];
    unsigned u4 = Hs[(size_t)s4 * 64 + lane];
    unsigned u5 = Hs[(size_t)s5 * 64 + lane];
    unsigned u6 = Hs[(size_t)s6 * 64 + lane];
    unsigned u7 = Hs[(size_t)s7 * 64 + lane];
    a0 += ((bflo(u0) + bflo(u1)) + (bflo(u2) + bflo(u3))) +
          ((bflo(u4) + bflo(u5)) + (bflo(u6) + bflo(u7)));
    a1 += ((bfhi(u0) + bfhi(u1)) + (bfhi(u2) + bfhi(u3))) +
          ((bfhi(u4) + bfhi(u5)) + (bfhi(u6) + bfhi(u7)));
  }
  for (; j + 4 <= end; j += 4) {
    int s0 = col[j], s1 = col[j + 1], s2 = col[j + 2], s3 = col[j + 3];
    unsigned u0 = Hs[(size_t)s0 * 64 + lane];
    unsigned u1 = Hs[(size_t)s1 * 64 + lane];
    unsigned u2 = Hs[(size_t)s2 * 64 + lane];
    unsigned u3 = Hs[(size_t)s3 * 64 + lane];
    a0 += (bflo(u0) + bflo(u1)) + (bflo(u2) + bflo(u3));
    a1 += (bfhi(u0) + bfhi(u1)) + (bfhi(u2) + bfhi(u3));
  }
  for (; j < end; ++j) {
    unsigned uu = Hs[(size_t)col[j] * 64 + lane];
    a0 += bflo(uu);
    a1 += bfhi(uu);
  }
  const float di = dis[node];
  const int c = lane * 2;
  float r0 = fmaxf(fmaf(a0, di, bias[c]), 0.f);
  float r1 = fmaxf(fmaf(a1, di, bias[c + 1]), 0.f);
  G[(size_t)node * 64 + lane] = f2bf(r0) | (f2bf(r1) << 16);
}

// layer2: f32 output to d_out, no relu
__global__ __launch_bounds__(256) void k_agg64(const unsigned* __restrict__ Hs,
                                               const int* __restrict__ rowptr,
                                               const int* __restrict__ col,
                                               const float* __restrict__ dis,
                                               const float* __restrict__ bias,
                                               float* __restrict__ out, int n) {
  const int node = (blockIdx.x * blockDim.x + threadIdx.x) >> 5;
  const int l = threadIdx.x & 31;
  if (node >= n) return;
  unsigned u = Hs[(size_t)node * 32 + l];
  float a0 = bflo(u), a1 = bfhi(u);
  int j = rowptr[node];
  const int end = rowptr[node + 1];
  for (; j + 8 <= end; j += 8) {
    int s0 = col[j], s1 = col[j + 1], s2 = col[j + 2], s3 = col[j + 3];
    int s4 = col[j + 4], s5 = col[j + 5], s6 = col[j + 6], s7 = col[j + 7];
    unsigned u0 = Hs[(size_t)s0 * 32 + l];
    unsigned u1 = Hs[(size_t)s1 * 32 + l];
    unsigned u2 = Hs[(size_t)s2 * 32 + l];
    unsigned u3 = Hs[(size_t)s3 * 32 + l];
    unsigned u4 = Hs[(size_t)s4 * 32 + l];
    unsigned u5 = Hs[(size_t)s5 * 32 + l];
    unsigned u6 = Hs[(size_t)s6 * 32 + l];
    unsigned u7 = Hs[(size_t)s7 * 32 + l];
    a0 += ((bflo(u0) + bflo(u1)) + (bflo(u2) + bflo(u3))) +
          ((bflo(u4) + bflo(u5)) + (bflo(u6) + bflo(u7)));
    a1 += ((bfhi(u0) + bfhi(u1)) + (bfhi(u2) + bfhi(u3))) +
          ((bfhi(u4) + bfhi(u5)) + (bfhi(u6) + bfhi(u7)));
  }
  for (; j + 4 <= end; j += 4) {
    int s0 = col[j], s1 = col[j + 1], s2 = col[j + 2], s3 = col[j + 3];
    unsigned u0 = Hs[(size_t)s0 * 32 + l];
    unsigned u1 = Hs[(size_t)s1 * 32 + l];
    unsigned u2 = Hs[(size_t)s2 * 32 + l];
    unsigned u3 = Hs[(size_t)s3 * 32 + l];
    a0 += (bflo(u0) + bflo(u1)) + (bflo(u2) + bflo(u3));
    a1 += (bfhi(u0) + bfhi(u1)) + (bfhi(u2) + bfhi(u3));
  }
  for (; j < end; ++j) {
    unsigned uu = Hs[(size_t)col[j] * 32 + l];
    a0 += bflo(uu);
    a1 += bfhi(uu);
  }
  const float di = dis[node];
  const int c = l * 2;
  float r0 = fmaf(a0, di, bias[c]);
  float r1 = fmaf(a1, di, bias[c + 1]);
  *(float2*)&out[(size_t)node * 64 + c] = make_float2(r0, r1);
}

// ---------------- launch ----------------

extern "C" void kernel_launch(void* const* d_in, const int* in_sizes, int n_in,
                              void* d_out, int out_size, void* d_ws, size_t ws_size,
                              hipStream_t stream) {
  const float* x  = (const float*)d_in[0];
  const int*   ei = (const int*)d_in[1];
  const float* W1 = (const float*)d_in[2];
  const float* b1 = (const float*)d_in[3];
  const float* W2 = (const float*)d_in[4];
  const float* b2 = (const float*)d_in[5];
  float* out = (float*)d_out;

  const int N = N_NODES, E = N_EDGES;
  const int* esrc = ei;
  const int* edst = ei + E;

  char* w = (char*)d_ws;
  auto alloc = [&](size_t bytes) -> char* {
    char* p = w;
    w += (bytes + 255) & ~(size_t)255;
    return p;
  };
  float* dis          = (float*)alloc((size_t)N * 4);
  int* rowptr         = (int*)alloc((size_t)(N + 1) * 4);
  int* cnt            = (int*)alloc((size_t)(N + 512) * 4);
  int* bcnt           = cnt + N;
  int* bsums          = (int*)alloc(512 * 4);
  int* col            = (int*)alloc((size_t)E * 4);
  unsigned* tmp       = (unsigned*)alloc((size_t)NBKT * CAP * 4);       // 7.2 MB
  unsigned short* h1s = (unsigned short*)alloc((size_t)N * HID_C * 2);  // 25.6 MB
  unsigned* g1        = (unsigned*)alloc((size_t)N * (HID_C / 2) * 4);  // 25.6 MB bf16x2
  unsigned short* h2s = (unsigned short*)alloc((size_t)N * OUT_C * 2);  // 12.8 MB
  unsigned short* W1h = (unsigned short*)alloc((size_t)IN_C * HID_C * 2);
  unsigned short* W1l = (unsigned short*)alloc((size_t)IN_C * HID_C * 2);
  unsigned short* W2h = (unsigned short*)alloc((size_t)HID_C * OUT_C * 2);
  unsigned short* W2l = (unsigned short*)alloc((size_t)HID_C * OUT_C * 2);

  const int nb = (N + 255) / 256;

  // CSR build
  hipMemsetAsync(cnt, 0, (size_t)(N + 512) * 4, stream);
  k_partA<<<(E + EPB - 1) / EPB, 256, 0, stream>>>(esrc, edst, cnt, bcnt, tmp, E);
  k_scan_block<<<nb, 256, 0, stream>>>(cnt, rowptr, bsums, dis, N);
  k_scan_sums<<<1, 512, 0, stream>>>(bsums, nb);
  k_add_off<<<(N + 1 + 255) / 256, 256, 0, stream>>>(rowptr, bsums, N, E);
  k_partB<<<NBKT, 256, 0, stream>>>(tmp, bcnt, rowptr, col, N);
  k_prepW<<<(IN_C * HID_C + HID_C * OUT_C + 255) / 256, 256, 0, stream>>>(
      W1, W2, W1h, W1l, W2h, W2l);

  // layer 1
  k_mfma1<<<(N + 63) / 64, 256, 0, stream>>>(x, W1h, W1l, dis, h1s, N);
  k_agg128<<<(N * 64 + 255) / 256, 256, 0, stream>>>((const unsigned*)h1s, rowptr, col,
                                                     dis, b1, g1, N);
  // layer 2
  k_mfma2<<<(N + 63) / 64, 256, 0, stream>>>(g1, W2h, W2l, dis, h2s, N);
  k_agg64<<<(N * 32 + 255) / 256, 256, 0, stream>>>((const unsigned*)h2s, rowptr, col,
                                                    dis, b2, out, N);
}

// Round 5
// 266.178 us; speedup vs baseline: 2.1627x; 1.2147x over previous
//
#include <hip/hip_runtime.h>

#define N_NODES 100000
#define N_EDGES 1600000
#define IN_C 128
#define HID_C 128
#define OUT_C 64

#define SH 8                 // bucket = dst >> 8 (256 nodes/bucket)
#define NBKT 391             // ceil(100000/256)
#define CAP 4608             // bucket capacity: mean 4096 + 8 sigma
#define EPB 4096             // edges per block in phase A
#define EPT 16               // EPB / 256

typedef __attribute__((ext_vector_type(8))) short bf16x8;
typedef __attribute__((ext_vector_type(4))) float f32x4;

// ---- bf16 helpers ----
static __device__ __forceinline__ unsigned f2bf(float f) {
  union { float f; unsigned u; } v; v.f = f;
  unsigned r = v.u + 0x7fffu + ((v.u >> 16) & 1u);
  return r >> 16;
}
static __device__ __forceinline__ float bf2f(unsigned hu) {
  union { unsigned u; float f; } v; v.u = hu << 16; return v.f;
}
static __device__ __forceinline__ float bflo(unsigned u) {
  union { unsigned u; float f; } v; v.u = u << 16; return v.f;
}
static __device__ __forceinline__ float bfhi(unsigned u) {
  union { unsigned u; float f; } v; v.u = u & 0xffff0000u; return v.f;
}

// ---------------- phase A: LDS-reorder radix partition by dst-bucket ----------------
// Coalesced writeout: staging is bucket-sorted, so consecutive slots of one
// bucket land at consecutive tmp addresses. No global per-node atomics.

__global__ __launch_bounds__(256) void k_partA(const int* __restrict__ src,
                                               const int* __restrict__ dst,
                                               int* __restrict__ bcnt,
                                               unsigned* __restrict__ tmp, int e) {
  __shared__ unsigned stage[EPB];        // 16 KB
  __shared__ unsigned short bid[EPB];    // 8 KB
  __shared__ int hist[NBKT];             // counts, then scatter cursors
  __shared__ int lstart[NBKT];           // local exclusive offsets
  __shared__ int base[NBKT];             // global run base within bucket
  __shared__ int ps[256];
  const int t = threadIdx.x;
  const int e0 = blockIdx.x * EPB;
  const int m = (e0 + EPB < e ? EPB : e - e0);

  for (int i = t; i < NBKT; i += 256) hist[i] = 0;
  __syncthreads();

  int rsrc[EPT], rdst[EPT];
#pragma unroll
  for (int i = 0; i < EPT; ++i) {
    int idx = e0 + i * 256 + t;
    if (idx < e) {
      rsrc[i] = src[idx];
      rdst[i] = dst[idx];
      atomicAdd(&hist[rdst[i] >> SH], 1);
    }
  }
  __syncthreads();

  // exclusive scan of hist (pairs per thread, Hillis-Steele on 256 partials)
  int a0 = (2 * t < NBKT) ? hist[2 * t] : 0;
  int a1 = (2 * t + 1 < NBKT) ? hist[2 * t + 1] : 0;
  ps[t] = a0 + a1;
  __syncthreads();
  for (int off = 1; off < 256; off <<= 1) {
    int add = (t >= off) ? ps[t - off] : 0;
    __syncthreads();
    ps[t] += add;
    __syncthreads();
  }
  int ex = ps[t] - (a0 + a1);
  if (2 * t < NBKT) lstart[2 * t] = ex;
  if (2 * t + 1 < NBKT) lstart[2 * t + 1] = ex + a0;

  // reserve global runs, zero scatter cursors
  for (int i = t; i < NBKT; i += 256) {
    int h = hist[i];
    base[i] = h ? atomicAdd(&bcnt[i], h) : 0;
    hist[i] = 0;
  }
  __syncthreads();

  // scatter into bucket-sorted staging
#pragma unroll
  for (int i = 0; i < EPT; ++i) {
    int idx = e0 + i * 256 + t;
    if (idx < e) {
      int d = rdst[i];
      int b = d >> SH;
      int pos = lstart[b] + atomicAdd(&hist[b], 1);
      stage[pos] = (unsigned)rsrc[i] | ((unsigned)(d & 255) << 17);
      bid[pos] = (unsigned short)b;
    }
  }
  __syncthreads();

  // linear writeout: coalesced within bucket runs
  for (int pos = t; pos < m; pos += 256) {
    int b = bid[pos];
    int slot = base[b] + (pos - lstart[b]);
    if (slot < CAP)  // 8-sigma safety clamp
      tmp[(size_t)b * CAP + slot] = stage[pos];
  }
}

// per-bucket degree count from partitioned tmp (replaces global count atomics)
__global__ __launch_bounds__(256) void k_cntb(const unsigned* __restrict__ tmp,
                                              const int* __restrict__ bcnt,
                                              int* __restrict__ cnt, int n) {
  __shared__ int h[256];
  const int b = blockIdx.x, t = threadIdx.x;
  h[t] = 0;
  __syncthreads();
  int m = bcnt[b];
  if (m > CAP) m = CAP;
  for (int j = t; j < m; j += 256)
    atomicAdd(&h[tmp[(size_t)b * CAP + j] >> 17], 1);
  __syncthreads();
  int node = (b << SH) + t;
  if (node < n) cnt[node] = h[t];
}

// per-256-block exclusive scan of cnt; also emits dis = rsqrt(cnt+1)
__global__ void k_scan_block(const int* __restrict__ cnt, int* __restrict__ rowptr,
                             int* __restrict__ bsums, float* __restrict__ dis, int n) {
  __shared__ int s[256];
  int t = threadIdx.x;
  int i = blockIdx.x * 256 + t;
  int v = (i < n) ? cnt[i] : 0;
  if (i < n) dis[i] = rsqrtf((float)(v + 1));
  s[t] = v;
  __syncthreads();
  for (int off = 1; off < 256; off <<= 1) {
    int add = (t >= off) ? s[t - off] : 0;
    __syncthreads();
    s[t] += add;
    __syncthreads();
  }
  if (i < n) rowptr[i] = s[t] - v;
  if (t == 255) bsums[blockIdx.x] = s[255];
}

__global__ void k_scan_sums(int* __restrict__ bsums, int nb) {
  __shared__ int s[512];
  int t = threadIdx.x;
  int v = (t < nb) ? bsums[t] : 0;
  s[t] = v;
  __syncthreads();
  for (int off = 1; off < 512; off <<= 1) {
    int add = (t >= off) ? s[t - off] : 0;
    __syncthreads();
    s[t] += add;
    __syncthreads();
  }
  if (t < nb) bsums[t] = s[t] - v;
}

__global__ void k_add_off(int* __restrict__ rowptr, const int* __restrict__ bsums,
                          int n, int e) {
  int i = blockIdx.x * blockDim.x + threadIdx.x;
  if (i < n) rowptr[i] += bsums[i >> 8];
  else if (i == n) rowptr[n] = e;
}

// phase B: bucket-local scatter to exact CSR slots (LDS cursors)
__global__ __launch_bounds__(256) void k_partB(const unsigned* __restrict__ tmp,
                                               const int* __restrict__ bcnt,
                                               const int* __restrict__ rowptr,
                                               int* __restrict__ col, int n) {
  __shared__ int cur[256];
  const int b = blockIdx.x;
  const int t = threadIdx.x;
  const int node = (b << SH) + t;
  cur[t] = (node < n) ? rowptr[node] : 0;
  __syncthreads();
  int m = bcnt[b];
  if (m > CAP) m = CAP;
  for (int j = t; j < m; j += 256) {
    unsigned v = tmp[(size_t)b * CAP + j];
    int pos = atomicAdd(&cur[v >> 17], 1);
    col[pos] = (int)(v & 0x1FFFFu);
  }
}

// ---------------- weight prep: transpose + split-bf16 (W = hi + lo) ----------------

__global__ void k_prepW(const float* __restrict__ W1, const float* __restrict__ W2,
                        unsigned short* __restrict__ W1h, unsigned short* __restrict__ W1l,
                        unsigned short* __restrict__ W2h, unsigned short* __restrict__ W2l) {
  int i = blockIdx.x * blockDim.x + threadIdx.x;
  if (i < IN_C * HID_C) {
    int k = i >> 7, c = i & 127;
    float w = W1[i];
    unsigned hi = f2bf(w);
    W1h[c * 128 + k] = (unsigned short)hi;
    W1l[c * 128 + k] = (unsigned short)f2bf(w - bf2f(hi));
  }
  int j = i - IN_C * HID_C;
  if (j >= 0 && j < HID_C * OUT_C) {
    int k = j >> 6, c = j & 63;
    float w = W2[j];
    unsigned hi = f2bf(w);
    W2h[c * 128 + k] = (unsigned short)hi;
    W2l[c * 128 + k] = (unsigned short)f2bf(w - bf2f(hi));
  }
}

// ---------------- MFMA GEMM layer 1: Hs = bf16( (f32 X @ W1) * dis[row] ) ----------------

__global__ __launch_bounds__(256) void k_mfma1(const float* __restrict__ X,
                                               const unsigned short* __restrict__ Wh,
                                               const unsigned short* __restrict__ Wl,
                                               const float* __restrict__ dis,
                                               unsigned short* __restrict__ Hs, int n) {
  __shared__ unsigned short xs[64 * 136];
  const int t = threadIdx.x;
  const int row0 = blockIdx.x * 64;
  for (int i = t; i < 64 * 32; i += 256) {
    int r = i >> 5, q = i & 31;
    float4 v = make_float4(0.f, 0.f, 0.f, 0.f);
    if (row0 + r < n) v = ((const float4*)(X + (size_t)(row0 + r) * IN_C))[q];
    unsigned p0 = f2bf(v.x) | (f2bf(v.y) << 16);
    unsigned p1 = f2bf(v.z) | (f2bf(v.w) << 16);
    *(uint2*)&xs[r * 136 + q * 4] = make_uint2(p0, p1);
  }
  __syncthreads();

  const int w = t >> 6, l = t & 63;
  const int wr = w * 16;
  const int lr = l & 15, lk = (l >> 4) * 8;
  f32x4 acc[8];
#pragma unroll
  for (int c = 0; c < 8; ++c) acc[c] = (f32x4){0.f, 0.f, 0.f, 0.f};

#pragma unroll
  for (int kb = 0; kb < 4; ++kb) {
    bf16x8 a = *(const bf16x8*)&xs[(wr + lr) * 136 + kb * 32 + lk];
#pragma unroll
    for (int c = 0; c < 8; ++c) {
      int col = c * 16 + lr;
      bf16x8 bh = *(const bf16x8*)&Wh[(size_t)col * 128 + kb * 32 + lk];
      bf16x8 bl = *(const bf16x8*)&Wl[(size_t)col * 128 + kb * 32 + lk];
      acc[c] = __builtin_amdgcn_mfma_f32_16x16x32_bf16(a, bh, acc[c], 0, 0, 0);
      acc[c] = __builtin_amdgcn_mfma_f32_16x16x32_bf16(a, bl, acc[c], 0, 0, 0);
    }
  }

  const int rbase = row0 + wr + (l >> 4) * 4;
  float dv[4];
#pragma unroll
  for (int j = 0; j < 4; ++j) dv[j] = (rbase + j < n) ? dis[rbase + j] : 0.f;
#pragma unroll
  for (int c = 0; c < 8; ++c) {
    int col = c * 16 + lr;
#pragma unroll
    for (int j = 0; j < 4; ++j) {
      int row = rbase + j;
      if (row < n) Hs[(size_t)row * HID_C + col] = (unsigned short)f2bf(acc[c][j] * dv[j]);
    }
  }
}

// ---------------- MFMA GEMM layer 2: Hs = bf16( (bf16 G @ W2) * dis[row] ) ----------------

__global__ __launch_bounds__(256) void k_mfma2(const unsigned* __restrict__ G,
                                               const unsigned short* __restrict__ Wh,
                                               const unsigned short* __restrict__ Wl,
                                               const float* __restrict__ dis,
                                               unsigned short* __restrict__ Hs, int n) {
  __shared__ unsigned short xs[64 * 136];
  const int t = threadIdx.x;
  const int row0 = blockIdx.x * 64;
  for (int i = t; i < 64 * 32; i += 256) {
    int r = i >> 5, q = i & 31;
    uint2 v = make_uint2(0u, 0u);
    if (row0 + r < n) v = *(const uint2*)&G[(size_t)(row0 + r) * 64 + q * 2];
    *(uint2*)&xs[r * 136 + q * 4] = v;
  }
  __syncthreads();

  const int w = t >> 6, l = t & 63;
  const int wr = w * 16;
  const int lr = l & 15, lk = (l >> 4) * 8;
  f32x4 acc[4];
#pragma unroll
  for (int c = 0; c < 4; ++c) acc[c] = (f32x4){0.f, 0.f, 0.f, 0.f};

#pragma unroll
  for (int kb = 0; kb < 4; ++kb) {
    bf16x8 a = *(const bf16x8*)&xs[(wr + lr) * 136 + kb * 32 + lk];
#pragma unroll
    for (int c = 0; c < 4; ++c) {
      int col = c * 16 + lr;
      bf16x8 bh = *(const bf16x8*)&Wh[(size_t)col * 128 + kb * 32 + lk];
      bf16x8 bl = *(const bf16x8*)&Wl[(size_t)col * 128 + kb * 32 + lk];
      acc[c] = __builtin_amdgcn_mfma_f32_16x16x32_bf16(a, bh, acc[c], 0, 0, 0);
      acc[c] = __builtin_amdgcn_mfma_f32_16x16x32_bf16(a, bl, acc[c], 0, 0, 0);
    }
  }

  const int rbase = row0 + wr + (l >> 4) * 4;
  float dv[4];
#pragma unroll
  for (int j = 0; j < 4; ++j) dv[j] = (rbase + j < n) ? dis[rbase + j] : 0.f;
#pragma unroll
  for (int c = 0; c < 4; ++c) {
    int col = c * 16 + lr;
#pragma unroll
    for (int j = 0; j < 4; ++j) {
      int row = rbase + j;
      if (row < n) Hs[(size_t)row * OUT_C + col] = (unsigned short)f2bf(acc[c][j] * dv[j]);
    }
  }
}

// ---------------- aggregation (bf16 pre-scaled rows, f32 accum) ----------------

__global__ __launch_bounds__(256) void k_agg128(const unsigned* __restrict__ Hs,
                                                const int* __restrict__ rowptr,
                                                const int* __restrict__ col,
                                                const float* __restrict__ dis,
                                                const float* __restrict__ bias,
                                                unsigned* __restrict__ G, int n) {
  const int node = (blockIdx.x * blockDim.x + threadIdx.x) >> 6;
  const int lane = threadIdx.x & 63;
  if (node >= n) return;
  unsigned u = Hs[(size_t)node * 64 + lane];
  float a0 = bflo(u), a1 = bfhi(u);
  int j = rowptr[node];
  const int end = rowptr[node + 1];
  for (; j + 8 <= end; j += 8) {
    int s0 = col[j], s1 = col[j + 1], s2 = col[j + 2], s3 = col[j + 3];
    int s4 = col[j + 4], s5 = col[j + 5], s6 = col[j + 6], s7 = col[j + 7];
    unsigned u0 = Hs[(size_t)s0 * 64 + lane];
    unsigned u1 = Hs[(size_t)s1 * 64 + lane];
    unsigned u2 = Hs[(size_t)s2 * 64 + lane];
    unsigned u3 = Hs[(size_t)s3 * 64 + lane];
    unsigned u4 = Hs[(size_t)s4 * 64 + lane];
    unsigned u5 = Hs[(size_t)s5 * 64 + lane];
    unsigned u6 = Hs[(size_t)s6 * 64 + lane];
    unsigned u7 = Hs[(size_t)s7 * 64 + lane];
    a0 += ((bflo(u0) + bflo(u1)) + (bflo(u2) + bflo(u3))) +
          ((bflo(u4) + bflo(u5)) + (bflo(u6) + bflo(u7)));
    a1 += ((bfhi(u0) + bfhi(u1)) + (bfhi(u2) + bfhi(u3))) +
          ((bfhi(u4) + bfhi(u5)) + (bfhi(u6) + bfhi(u7)));
  }
  for (; j + 4 <= end; j += 4) {
    int s0 = col[j], s1 = col[j + 1], s2 = col[j + 2], s3 = col[j + 3];
    unsigned u0 = Hs[(size_t)s0 * 64 + lane];
    unsigned u1 = Hs[(size_t)s1 * 64 + lane];
    unsigned u2 = Hs[(size_t)s2 * 64 + lane];
    unsigned u3 = Hs[(size_t)s3 * 64 + lane];
    a0 += (bflo(u0) + bflo(u1)) + (bflo(u2) + bflo(u3));
    a1 += (bfhi(u0) + bfhi(u1)) + (bfhi(u2) + bfhi(u3));
  }
  for (; j < end; ++j) {
    unsigned uu = Hs[(size_t)col[j] * 64 + lane];
    a0 += bflo(uu);
    a1 += bfhi(uu);
  }
  const float di = dis[node];
  const int c = lane * 2;
  float r0 = fmaxf(fmaf(a0, di, bias[c]), 0.f);
  float r1 = fmaxf(fmaf(a1, di, bias[c + 1]), 0.f);
  G[(size_t)node * 64 + lane] = f2bf(r0) | (f2bf(r1) << 16);
}

__global__ __launch_bounds__(256) void k_agg64(const unsigned* __restrict__ Hs,
                                               const int* __restrict__ rowptr,
                                               const int* __restrict__ col,
                                               const float* __restrict__ dis,
                                               const float* __restrict__ bias,
                                               float* __restrict__ out, int n) {
  const int node = (blockIdx.x * blockDim.x + threadIdx.x) >> 5;
  const int l = threadIdx.x & 31;
  if (node >= n) return;
  unsigned u = Hs[(size_t)node * 32 + l];
  float a0 = bflo(u), a1 = bfhi(u);
  int j = rowptr[node];
  const int end = rowptr[node + 1];
  for (; j + 8 <= end; j += 8) {
    int s0 = col[j], s1 = col[j + 1], s2 = col[j + 2], s3 = col[j + 3];
    int s4 = col[j + 4], s5 = col[j + 5], s6 = col[j + 6], s7 = col[j + 7];
    unsigned u0 = Hs[(size_t)s0 * 32 + l];
    unsigned u1 = Hs[(size_t)s1 * 32 + l];
    unsigned u2 = Hs[(size_t)s2 * 32 + l];
    unsigned u3 = Hs[(size_t)s3 * 32 + l];
    unsigned u4 = Hs[(size_t)s4 * 32 + l];
    unsigned u5 = Hs[(size_t)s5 * 32 + l];
    unsigned u6 = Hs[(size_t)s6 * 32 + l];
    unsigned u7 = Hs[(size_t)s7 * 32 + l];
    a0 += ((bflo(u0) + bflo(u1)) + (bflo(u2) + bflo(u3))) +
          ((bflo(u4) + bflo(u5)) + (bflo(u6) + bflo(u7)));
    a1 += ((bfhi(u0) + bfhi(u1)) + (bfhi(u2) + bfhi(u3))) +
          ((bfhi(u4) + bfhi(u5)) + (bfhi(u6) + bfhi(u7)));
  }
  for (; j + 4 <= end; j += 4) {
    int s0 = col[j], s1 = col[j + 1], s2 = col[j + 2], s3 = col[j + 3];
    unsigned u0 = Hs[(size_t)s0 * 32 + l];
    unsigned u1 = Hs[(size_t)s1 * 32 + l];
    unsigned u2 = Hs[(size_t)s2 * 32 + l];
    unsigned u3 = Hs[(size_t)s3 * 32 + l];
    a0 += (bflo(u0) + bflo(u1)) + (bflo(u2) + bflo(u3));
    a1 += (bfhi(u0) + bfhi(u1)) + (bfhi(u2) + bfhi(u3));
  }
  for (; j < end; ++j) {
    unsigned uu = Hs[(size_t)col[j] * 32 + l];
    a0 += bflo(uu);
    a1 += bfhi(uu);
  }
  const float di = dis[node];
  const int c = l * 2;
  float r0 = fmaf(a0, di, bias[c]);
  float r1 = fmaf(a1, di, bias[c + 1]);
  *(float2*)&out[(size_t)node * 64 + c] = make_float2(r0, r1);
}

// ---------------- launch ----------------

extern "C" void kernel_launch(void* const* d_in, const int* in_sizes, int n_in,
                              void* d_out, int out_size, void* d_ws, size_t ws_size,
                              hipStream_t stream) {
  const float* x  = (const float*)d_in[0];
  const int*   ei = (const int*)d_in[1];
  const float* W1 = (const float*)d_in[2];
  const float* b1 = (const float*)d_in[3];
  const float* W2 = (const float*)d_in[4];
  const float* b2 = (const float*)d_in[5];
  float* out = (float*)d_out;

  const int N = N_NODES, E = N_EDGES;
  const int* esrc = ei;
  const int* edst = ei + E;

  char* w = (char*)d_ws;
  auto alloc = [&](size_t bytes) -> char* {
    char* p = w;
    w += (bytes + 255) & ~(size_t)255;
    return p;
  };
  float* dis          = (float*)alloc((size_t)N * 4);
  int* rowptr         = (int*)alloc((size_t)(N + 1) * 4);
  int* cnt            = (int*)alloc((size_t)N * 4);
  int* bcnt           = (int*)alloc((size_t)NBKT * 4);
  int* bsums          = (int*)alloc(512 * 4);
  int* col            = (int*)alloc((size_t)E * 4);
  unsigned* tmp       = (unsigned*)alloc((size_t)NBKT * CAP * 4);       // 7.2 MB
  unsigned short* h1s = (unsigned short*)alloc((size_t)N * HID_C * 2);  // 25.6 MB
  unsigned* g1        = (unsigned*)alloc((size_t)N * (HID_C / 2) * 4);  // 25.6 MB bf16x2
  unsigned short* h2s = (unsigned short*)alloc((size_t)N * OUT_C * 2);  // 12.8 MB
  unsigned short* W1h = (unsigned short*)alloc((size_t)IN_C * HID_C * 2);
  unsigned short* W1l = (unsigned short*)alloc((size_t)IN_C * HID_C * 2);
  unsigned short* W2h = (unsigned short*)alloc((size_t)HID_C * OUT_C * 2);
  unsigned short* W2l = (unsigned short*)alloc((size_t)HID_C * OUT_C * 2);

  const int nb = (N + 255) / 256;

  // CSR build
  hipMemsetAsync(bcnt, 0, (size_t)NBKT * 4, stream);
  k_partA<<<(E + EPB - 1) / EPB, 256, 0, stream>>>(esrc, edst, bcnt, tmp, E);
  k_cntb<<<NBKT, 256, 0, stream>>>(tmp, bcnt, cnt, N);
  k_scan_block<<<nb, 256, 0, stream>>>(cnt, rowptr, bsums, dis, N);
  k_scan_sums<<<1, 512, 0, stream>>>(bsums, nb);
  k_add_off<<<(N + 1 + 255) / 256, 256, 0, stream>>>(rowptr, bsums, N, E);
  k_partB<<<NBKT, 256, 0, stream>>>(tmp, bcnt, rowptr, col, N);
  k_prepW<<<(IN_C * HID_C + HID_C * OUT_C + 255) / 256, 256, 0, stream>>>(
      W1, W2, W1h, W1l, W2h, W2l);

  // layer 1
  k_mfma1<<<(N + 63) / 64, 256, 0, stream>>>(x, W1h, W1l, dis, h1s, N);
  k_agg128<<<(N * 64 + 255) / 256, 256, 0, stream>>>((const unsigned*)h1s, rowptr, col,
                                                     dis, b1, g1, N);
  // layer 2
  k_mfma2<<<(N + 63) / 64, 256, 0, stream>>>(g1, W2h, W2l, dis, h2s, N);
  k_agg64<<<(N * 32 + 255) / 256, 256, 0, stream>>>((const unsigned*)h2s, rowptr, col,
                                                    dis, b2, out, N);
}

// Round 6
// 208.271 us; speedup vs baseline: 2.7640x; 1.2780x over previous
//
#include <hip/hip_runtime.h>

#define N_NODES 100000
#define N_EDGES 1600000
#define IN_C 128
#define HID_C 128
#define OUT_C 64

#define SH 8                 // bucket = dst >> 8 (256 nodes/bucket)
#define NBKT 391             // ceil(100000/256)
#define CAP 4608             // bucket capacity: mean 4096 + 8 sigma
#define EPB 4096             // edges per block in phase A
#define EPT 16               // EPB / 256

typedef __attribute__((ext_vector_type(8))) short bf16x8;
typedef __attribute__((ext_vector_type(4))) float f32x4;

// ---- bf16 helpers ----
static __device__ __forceinline__ unsigned f2bf(float f) {
  union { float f; unsigned u; } v; v.f = f;
  unsigned r = v.u + 0x7fffu + ((v.u >> 16) & 1u);
  return r >> 16;
}
static __device__ __forceinline__ float bf2f(unsigned hu) {
  union { unsigned u; float f; } v; v.u = hu << 16; return v.f;
}
static __device__ __forceinline__ float bflo(unsigned u) {
  union { unsigned u; float f; } v; v.u = u << 16; return v.f;
}
static __device__ __forceinline__ float bfhi(unsigned u) {
  union { unsigned u; float f; } v; v.u = u & 0xffff0000u; return v.f;
}

// ---------------- phase A: LDS-reorder radix partition by dst-bucket ----------------

__global__ __launch_bounds__(256) void k_partA(const int* __restrict__ src,
                                               const int* __restrict__ dst,
                                               int* __restrict__ bcnt,
                                               unsigned* __restrict__ tmp, int e) {
  __shared__ unsigned stage[EPB];        // 16 KB
  __shared__ unsigned short bid[EPB];    // 8 KB
  __shared__ int hist[NBKT];
  __shared__ int lstart[NBKT];
  __shared__ int base[NBKT];
  __shared__ int ps[256];
  const int t = threadIdx.x;
  const int e0 = blockIdx.x * EPB;
  const int m = (e0 + EPB < e ? EPB : e - e0);

  for (int i = t; i < NBKT; i += 256) hist[i] = 0;
  __syncthreads();

  int rsrc[EPT], rdst[EPT];
#pragma unroll
  for (int i = 0; i < EPT; ++i) {
    int idx = e0 + i * 256 + t;
    if (idx < e) {
      rsrc[i] = src[idx];
      rdst[i] = dst[idx];
      atomicAdd(&hist[rdst[i] >> SH], 1);
    }
  }
  __syncthreads();

  int a0 = (2 * t < NBKT) ? hist[2 * t] : 0;
  int a1 = (2 * t + 1 < NBKT) ? hist[2 * t + 1] : 0;
  ps[t] = a0 + a1;
  __syncthreads();
  for (int off = 1; off < 256; off <<= 1) {
    int add = (t >= off) ? ps[t - off] : 0;
    __syncthreads();
    ps[t] += add;
    __syncthreads();
  }
  int ex = ps[t] - (a0 + a1);
  if (2 * t < NBKT) lstart[2 * t] = ex;
  if (2 * t + 1 < NBKT) lstart[2 * t + 1] = ex + a0;

  for (int i = t; i < NBKT; i += 256) {
    int h = hist[i];
    base[i] = h ? atomicAdd(&bcnt[i], h) : 0;
    hist[i] = 0;
  }
  __syncthreads();

#pragma unroll
  for (int i = 0; i < EPT; ++i) {
    int idx = e0 + i * 256 + t;
    if (idx < e) {
      int d = rdst[i];
      int b = d >> SH;
      int pos = lstart[b] + atomicAdd(&hist[b], 1);
      stage[pos] = (unsigned)rsrc[i] | ((unsigned)(d & 255) << 17);
      bid[pos] = (unsigned short)b;
    }
  }
  __syncthreads();

  for (int pos = t; pos < m; pos += 256) {
    int b = bid[pos];
    int slot = base[b] + (pos - lstart[b]);
    if (slot < CAP)  // 8-sigma safety clamp
      tmp[(size_t)b * CAP + slot] = stage[pos];
  }
}

// per-bucket degree count from partitioned tmp
__global__ __launch_bounds__(256) void k_cntb(const unsigned* __restrict__ tmp,
                                              const int* __restrict__ bcnt,
                                              int* __restrict__ cnt, int n) {
  __shared__ int h[256];
  const int b = blockIdx.x, t = threadIdx.x;
  h[t] = 0;
  __syncthreads();
  int m = bcnt[b];
  if (m > CAP) m = CAP;
  for (int j = t; j < m; j += 256)
    atomicAdd(&h[tmp[(size_t)b * CAP + j] >> 17], 1);
  __syncthreads();
  int node = (b << SH) + t;
  if (node < n) cnt[node] = h[t];
}

// per-256-block exclusive scan of cnt; also emits dis = rsqrt(cnt+1)
__global__ void k_scan_block(const int* __restrict__ cnt, int* __restrict__ rowptr,
                             int* __restrict__ bsums, float* __restrict__ dis, int n) {
  __shared__ int s[256];
  int t = threadIdx.x;
  int i = blockIdx.x * 256 + t;
  int v = (i < n) ? cnt[i] : 0;
  if (i < n) dis[i] = rsqrtf((float)(v + 1));
  s[t] = v;
  __syncthreads();
  for (int off = 1; off < 256; off <<= 1) {
    int add = (t >= off) ? s[t - off] : 0;
    __syncthreads();
    s[t] += add;
    __syncthreads();
  }
  if (i < n) rowptr[i] = s[t] - v;
  if (t == 255) bsums[blockIdx.x] = s[255];
}

__global__ void k_scan_sums(int* __restrict__ bsums, int nb) {
  __shared__ int s[512];
  int t = threadIdx.x;
  int v = (t < nb) ? bsums[t] : 0;
  s[t] = v;
  __syncthreads();
  for (int off = 1; off < 512; off <<= 1) {
    int add = (t >= off) ? s[t - off] : 0;
    __syncthreads();
    s[t] += add;
    __syncthreads();
  }
  if (t < nb) bsums[t] = s[t] - v;
}

__global__ void k_add_off(int* __restrict__ rowptr, const int* __restrict__ bsums,
                          int n, int e) {
  int i = blockIdx.x * blockDim.x + threadIdx.x;
  if (i < n) rowptr[i] += bsums[i >> 8];
  else if (i == n) rowptr[n] = e;
}

// phase B: bucket-local scatter to exact CSR slots (LDS cursors)
__global__ __launch_bounds__(256) void k_partB(const unsigned* __restrict__ tmp,
                                               const int* __restrict__ bcnt,
                                               const int* __restrict__ rowptr,
                                               int* __restrict__ col, int n) {
  __shared__ int cur[256];
  const int b = blockIdx.x;
  const int t = threadIdx.x;
  const int node = (b << SH) + t;
  cur[t] = (node < n) ? rowptr[node] : 0;
  __syncthreads();
  int m = bcnt[b];
  if (m > CAP) m = CAP;
  for (int j = t; j < m; j += 256) {
    unsigned v = tmp[(size_t)b * CAP + j];
    int pos = atomicAdd(&cur[v >> 17], 1);
    col[pos] = (int)(v & 0x1FFFFu);
  }
}

// ---------------- weight prep: transpose + split-bf16 (W = hi + lo) ----------------

__global__ void k_prepW(const float* __restrict__ W1, const float* __restrict__ W2,
                        unsigned short* __restrict__ W1h, unsigned short* __restrict__ W1l,
                        unsigned short* __restrict__ W2h, unsigned short* __restrict__ W2l) {
  int i = blockIdx.x * blockDim.x + threadIdx.x;
  if (i < IN_C * HID_C) {
    int k = i >> 7, c = i & 127;
    float w = W1[i];
    unsigned hi = f2bf(w);
    W1h[c * 128 + k] = (unsigned short)hi;
    W1l[c * 128 + k] = (unsigned short)f2bf(w - bf2f(hi));
  }
  int j = i - IN_C * HID_C;
  if (j >= 0 && j < HID_C * OUT_C) {
    int k = j >> 6, c = j & 63;
    float w = W2[j];
    unsigned hi = f2bf(w);
    W2h[c * 128 + k] = (unsigned short)hi;
    W2l[c * 128 + k] = (unsigned short)f2bf(w - bf2f(hi));
  }
}

// ---------------- MFMA GEMM layer 1: Hs = bf16( (f32 X @ W1) * dis[row] ) ----------------
// 4 waves x 32 cols each; weight fragments register-resident (loaded once/block).

__global__ __launch_bounds__(256) void k_mfma1(const float* __restrict__ X,
                                               const unsigned short* __restrict__ Wh,
                                               const unsigned short* __restrict__ Wl,
                                               const float* __restrict__ dis,
                                               unsigned short* __restrict__ Hs, int n) {
  __shared__ unsigned short xs[64 * 136];
  const int t = threadIdx.x;
  const int w = t >> 6, l = t & 63;
  const int lr = l & 15, lk = (l >> 4) * 8;
  const int row0 = blockIdx.x * 64;

  // hoist weights: wave w owns cols [w*32, w*32+32)
  bf16x8 Bh[2][4], Bl[2][4];
#pragma unroll
  for (int c2 = 0; c2 < 2; ++c2)
#pragma unroll
    for (int kb = 0; kb < 4; ++kb) {
      int colw = w * 32 + c2 * 16 + lr;
      Bh[c2][kb] = *(const bf16x8*)&Wh[(size_t)colw * 128 + kb * 32 + lk];
      Bl[c2][kb] = *(const bf16x8*)&Wl[(size_t)colw * 128 + kb * 32 + lk];
    }

  for (int i = t; i < 64 * 32; i += 256) {
    int r = i >> 5, q = i & 31;
    float4 v = make_float4(0.f, 0.f, 0.f, 0.f);
    if (row0 + r < n) v = ((const float4*)(X + (size_t)(row0 + r) * IN_C))[q];
    unsigned p0 = f2bf(v.x) | (f2bf(v.y) << 16);
    unsigned p1 = f2bf(v.z) | (f2bf(v.w) << 16);
    *(uint2*)&xs[r * 136 + q * 4] = make_uint2(p0, p1);
  }
  __syncthreads();

#pragma unroll
  for (int rst = 0; rst < 4; ++rst) {
    bf16x8 a[4];
#pragma unroll
    for (int kb = 0; kb < 4; ++kb)
      a[kb] = *(const bf16x8*)&xs[(rst * 16 + lr) * 136 + kb * 32 + lk];
    f32x4 acc0 = (f32x4){0.f, 0.f, 0.f, 0.f};
    f32x4 acc1 = (f32x4){0.f, 0.f, 0.f, 0.f};
#pragma unroll
    for (int kb = 0; kb < 4; ++kb) {
      acc0 = __builtin_amdgcn_mfma_f32_16x16x32_bf16(a[kb], Bh[0][kb], acc0, 0, 0, 0);
      acc1 = __builtin_amdgcn_mfma_f32_16x16x32_bf16(a[kb], Bh[1][kb], acc1, 0, 0, 0);
      acc0 = __builtin_amdgcn_mfma_f32_16x16x32_bf16(a[kb], Bl[0][kb], acc0, 0, 0, 0);
      acc1 = __builtin_amdgcn_mfma_f32_16x16x32_bf16(a[kb], Bl[1][kb], acc1, 0, 0, 0);
    }
    const int rbase = row0 + rst * 16 + (l >> 4) * 4;  // C/D: col=lane&15, row=(lane>>4)*4+reg
    float dv[4];
#pragma unroll
    for (int j = 0; j < 4; ++j) dv[j] = (rbase + j < n) ? dis[rbase + j] : 0.f;
#pragma unroll
    for (int c2 = 0; c2 < 2; ++c2) {
      int colw = w * 32 + c2 * 16 + lr;
      const f32x4& acc = c2 ? acc1 : acc0;
#pragma unroll
      for (int j = 0; j < 4; ++j) {
        int row = rbase + j;
        if (row < n) Hs[(size_t)row * HID_C + colw] = (unsigned short)f2bf(acc[j] * dv[j]);
      }
    }
  }
}

// ---------------- MFMA GEMM layer 2: Hs = bf16( (bf16 G @ W2) * dis[row] ) ----------------
// 4 waves x 16 cols each; weights register-resident.

__global__ __launch_bounds__(256) void k_mfma2(const unsigned* __restrict__ G,
                                               const unsigned short* __restrict__ Wh,
                                               const unsigned short* __restrict__ Wl,
                                               const float* __restrict__ dis,
                                               unsigned short* __restrict__ Hs, int n) {
  __shared__ unsigned short xs[64 * 136];
  const int t = threadIdx.x;
  const int w = t >> 6, l = t & 63;
  const int lr = l & 15, lk = (l >> 4) * 8;
  const int row0 = blockIdx.x * 64;

  bf16x8 Bh[4], Bl[4];
#pragma unroll
  for (int kb = 0; kb < 4; ++kb) {
    int colw = w * 16 + lr;
    Bh[kb] = *(const bf16x8*)&Wh[(size_t)colw * 128 + kb * 32 + lk];
    Bl[kb] = *(const bf16x8*)&Wl[(size_t)colw * 128 + kb * 32 + lk];
  }

  for (int i = t; i < 64 * 32; i += 256) {
    int r = i >> 5, q = i & 31;
    uint2 v = make_uint2(0u, 0u);
    if (row0 + r < n) v = *(const uint2*)&G[(size_t)(row0 + r) * 64 + q * 2];
    *(uint2*)&xs[r * 136 + q * 4] = v;
  }
  __syncthreads();

#pragma unroll
  for (int rst = 0; rst < 4; ++rst) {
    bf16x8 a[4];
#pragma unroll
    for (int kb = 0; kb < 4; ++kb)
      a[kb] = *(const bf16x8*)&xs[(rst * 16 + lr) * 136 + kb * 32 + lk];
    f32x4 acc = (f32x4){0.f, 0.f, 0.f, 0.f};
#pragma unroll
    for (int kb = 0; kb < 4; ++kb) {
      acc = __builtin_amdgcn_mfma_f32_16x16x32_bf16(a[kb], Bh[kb], acc, 0, 0, 0);
      acc = __builtin_amdgcn_mfma_f32_16x16x32_bf16(a[kb], Bl[kb], acc, 0, 0, 0);
    }
    const int rbase = row0 + rst * 16 + (l >> 4) * 4;
    const int colw = w * 16 + lr;
#pragma unroll
    for (int j = 0; j < 4; ++j) {
      int row = rbase + j;
      if (row < n) Hs[(size_t)row * OUT_C + colw] =
          (unsigned short)f2bf(acc[j] * dis[row]);
    }
  }
}

// ---------------- aggregation (bf16 pre-scaled rows, f32 accum) ----------------

__global__ __launch_bounds__(256) void k_agg128(const unsigned* __restrict__ Hs,
                                                const int* __restrict__ rowptr,
                                                const int* __restrict__ col,
                                                const float* __restrict__ dis,
                                                const float* __restrict__ bias,
                                                unsigned* __restrict__ G, int n) {
  const int node = (blockIdx.x * blockDim.x + threadIdx.x) >> 6;
  const int lane = threadIdx.x & 63;
  if (node >= n) return;
  unsigned u = Hs[(size_t)node * 64 + lane];
  float a0 = bflo(u), a1 = bfhi(u);
  int j = rowptr[node];
  const int end = rowptr[node + 1];
  for (; j + 8 <= end; j += 8) {
    int s0 = col[j], s1 = col[j + 1], s2 = col[j + 2], s3 = col[j + 3];
    int s4 = col[j + 4], s5 = col[j + 5], s6 = col[j + 6], s7 = col[j + 7];
    unsigned u0 = Hs[(size_t)s0 * 64 + lane];
    unsigned u1 = Hs[(size_t)s1 * 64 + lane];
    unsigned u2 = Hs[(size_t)s2 * 64 + lane];
    unsigned u3 = Hs[(size_t)s3 * 64 + lane];
    unsigned u4 = Hs[(size_t)s4 * 64 + lane];
    unsigned u5 = Hs[(size_t)s5 * 64 + lane];
    unsigned u6 = Hs[(size_t)s6 * 64 + lane];
    unsigned u7 = Hs[(size_t)s7 * 64 + lane];
    a0 += ((bflo(u0) + bflo(u1)) + (bflo(u2) + bflo(u3))) +
          ((bflo(u4) + bflo(u5)) + (bflo(u6) + bflo(u7)));
    a1 += ((bfhi(u0) + bfhi(u1)) + (bfhi(u2) + bfhi(u3))) +
          ((bfhi(u4) + bfhi(u5)) + (bfhi(u6) + bfhi(u7)));
  }
  for (; j + 4 <= end; j += 4) {
    int s0 = col[j], s1 = col[j + 1], s2 = col[j + 2], s3 = col[j + 3];
    unsigned u0 = Hs[(size_t)s0 * 64 + lane];
    unsigned u1 = Hs[(size_t)s1 * 64 + lane];
    unsigned u2 = Hs[(size_t)s2 * 64 + lane];
    unsigned u3 = Hs[(size_t)s3 * 64 + lane];
    a0 += (bflo(u0) + bflo(u1)) + (bflo(u2) + bflo(u3));
    a1 += (bfhi(u0) + bfhi(u1)) + (bfhi(u2) + bfhi(u3));
  }
  for (; j < end; ++j) {
    unsigned uu = Hs[(size_t)col[j] * 64 + lane];
    a0 += bflo(uu);
    a1 += bfhi(uu);
  }
  const float di = dis[node];
  const int c = lane * 2;
  float r0 = fmaxf(fmaf(a0, di, bias[c]), 0.f);
  float r1 = fmaxf(fmaf(a1, di, bias[c + 1]), 0.f);
  G[(size_t)node * 64 + lane] = f2bf(r0) | (f2bf(r1) << 16);
}

__global__ __launch_bounds__(256) void k_agg64(const unsigned* __restrict__ Hs,
                                               const int* __restrict__ rowptr,
                                               const int* __restrict__ col,
                                               const float* __restrict__ dis,
                                               const float* __restrict__ bias,
                                               float* __restrict__ out, int n) {
  const int node = (blockIdx.x * blockDim.x + threadIdx.x) >> 5;
  const int l = threadIdx.x & 31;
  if (node >= n) return;
  unsigned u = Hs[(size_t)node * 32 + l];
  float a0 = bflo(u), a1 = bfhi(u);
  int j = rowptr[node];
  const int end = rowptr[node + 1];
  for (; j + 8 <= end; j += 8) {
    int s0 = col[j], s1 = col[j + 1], s2 = col[j + 2], s3 = col[j + 3];
    int s4 = col[j + 4], s5 = col[j + 5], s6 = col[j + 6], s7 = col[j + 7];
    unsigned u0 = Hs[(size_t)s0 * 32 + l];
    unsigned u1 = Hs[(size_t)s1 * 32 + l];
    unsigned u2 = Hs[(size_t)s2 * 32 + l];
    unsigned u3 = Hs[(size_t)s3 * 32 + l];
    unsigned u4 = Hs[(size_t)s4 * 32 + l];
    unsigned u5 = Hs[(size_t)s5 * 32 + l];
    unsigned u6 = Hs[(size_t)s6 * 32 + l];
    unsigned u7 = Hs[(size_t)s7 * 32 + l];
    a0 += ((bflo(u0) + bflo(u1)) + (bflo(u2) + bflo(u3))) +
          ((bflo(u4) + bflo(u5)) + (bflo(u6) + bflo(u7)));
    a1 += ((bfhi(u0) + bfhi(u1)) + (bfhi(u2) + bfhi(u3))) +
          ((bfhi(u4) + bfhi(u5)) + (bfhi(u6) + bfhi(u7)));
  }
  for (; j + 4 <= end; j += 4) {
    int s0 = col[j], s1 = col[j + 1], s2 = col[j + 2], s3 = col[j + 3];
    unsigned u0 = Hs[(size_t)s0 * 32 + l];
    unsigned u1 = Hs[(size_t)s1 * 32 + l];
    unsigned u2 = Hs[(size_t)s2 * 32 + l];
    unsigned u3 = Hs[(size_t)s3 * 32 + l];
    a0 += (bflo(u0) + bflo(u1)) + (bflo(u2) + bflo(u3));
    a1 += (bfhi(u0) + bfhi(u1)) + (bfhi(u2) + bfhi(u3));
  }
  for (; j < end; ++j) {
    unsigned uu = Hs[(size_t)col[j] * 32 + l];
    a0 += bflo(uu);
    a1 += bfhi(uu);
  }
  const float di = dis[node];
  const int c = l * 2;
  float r0 = fmaf(a0, di, bias[c]);
  float r1 = fmaf(a1, di, bias[c + 1]);
  *(float2*)&out[(size_t)node * 64 + c] = make_float2(r0, r1);
}

// ---------------- launch ----------------

extern "C" void kernel_launch(void* const* d_in, const int* in_sizes, int n_in,
                              void* d_out, int out_size, void* d_ws, size_t ws_size,
                              hipStream_t stream) {
  const float* x  = (const float*)d_in[0];
  const int*   ei = (const int*)d_in[1];
  const float* W1 = (const float*)d_in[2];
  const float* b1 = (const float*)d_in[3];
  const float* W2 = (const float*)d_in[4];
  const float* b2 = (const float*)d_in[5];
  float* out = (float*)d_out;

  const int N = N_NODES, E = N_EDGES;
  const int* esrc = ei;
  const int* edst = ei + E;

  char* w = (char*)d_ws;
  auto alloc = [&](size_t bytes) -> char* {
    char* p = w;
    w += (bytes + 255) & ~(size_t)255;
    return p;
  };
  float* dis          = (float*)alloc((size_t)N * 4);
  int* rowptr         = (int*)alloc((size_t)(N + 1) * 4);
  int* cnt            = (int*)alloc((size_t)N * 4);
  int* bcnt           = (int*)alloc((size_t)NBKT * 4);
  int* bsums          = (int*)alloc(512 * 4);
  int* col            = (int*)alloc((size_t)E * 4);
  unsigned* tmp       = (unsigned*)alloc((size_t)NBKT * CAP * 4);       // 7.2 MB
  unsigned short* h1s = (unsigned short*)alloc((size_t)N * HID_C * 2);  // 25.6 MB
  unsigned* g1        = (unsigned*)alloc((size_t)N * (HID_C / 2) * 4);  // 25.6 MB bf16x2
  unsigned short* h2s = (unsigned short*)alloc((size_t)N * OUT_C * 2);  // 12.8 MB
  unsigned short* W1h = (unsigned short*)alloc((size_t)IN_C * HID_C * 2);
  unsigned short* W1l = (unsigned short*)alloc((size_t)IN_C * HID_C * 2);
  unsigned short* W2h = (unsigned short*)alloc((size_t)HID_C * OUT_C * 2);
  unsigned short* W2l = (unsigned short*)alloc((size_t)HID_C * OUT_C * 2);

  const int nb = (N + 255) / 256;

  // CSR build
  hipMemsetAsync(bcnt, 0, (size_t)NBKT * 4, stream);
  k_partA<<<(E + EPB - 1) / EPB, 256, 0, stream>>>(esrc, edst, bcnt, tmp, E);
  k_cntb<<<NBKT, 256, 0, stream>>>(tmp, bcnt, cnt, N);
  k_scan_block<<<nb, 256, 0, stream>>>(cnt, rowptr, bsums, dis, N);
  k_scan_sums<<<1, 512, 0, stream>>>(bsums, nb);
  k_add_off<<<(N + 1 + 255) / 256, 256, 0, stream>>>(rowptr, bsums, N, E);
  k_partB<<<NBKT, 256, 0, stream>>>(tmp, bcnt, rowptr, col, N);
  k_prepW<<<(IN_C * HID_C + HID_C * OUT_C + 255) / 256, 256, 0, stream>>>(
      W1, W2, W1h, W1l, W2h, W2l);

  // layer 1
  k_mfma1<<<(N + 63) / 64, 256, 0, stream>>>(x, W1h, W1l, dis, h1s, N);
  k_agg128<<<(N * 64 + 255) / 256, 256, 0, stream>>>((const unsigned*)h1s, rowptr, col,
                                                     dis, b1, g1, N);
  // layer 2
  k_mfma2<<<(N + 63) / 64, 256, 0, stream>>>(g1, W2h, W2l, dis, h2s, N);
  k_agg64<<<(N * 32 + 255) / 256, 256, 0, stream>>>((const unsigned*)h2s, rowptr, col,
                                                    dis, b2, out, N);
}